// Round 14
// baseline (227.336 us; speedup 1.0000x reference)
//
#include <hip/hip_runtime.h>
#include <hip/hip_bf16.h>
#include <math.h>

typedef __attribute__((ext_vector_type(4))) float f32x4;
typedef __attribute__((ext_vector_type(8))) short bf16x8;

#define N_ROWS 8192
#define D 256
#define MSHIFT 16.0f
#define NKB 8
#define KRANGE (N_ROWS / NKB)     // 1024
#define NSTEP (KRANGE / 32)       // 32 (BK=32)

__device__ __forceinline__ unsigned short f2bf(float f) {
    unsigned int u = __float_as_uint(f);
    unsigned int r = u + 0x7FFFu + ((u >> 16) & 1u);
    return (unsigned short)(r >> 16);
}
__device__ __forceinline__ float bf2f(unsigned short h) {
    return __uint_as_float(((unsigned int)h) << 16);
}

__device__ __forceinline__ float breduce_sum256(float v, float* sb) {
#pragma unroll
    for (int off = 32; off; off >>= 1) v += __shfl_down(v, off);
    int wid = threadIdx.x >> 6;
    __syncthreads();
    if ((threadIdx.x & 63) == 0) sb[wid] = v;
    __syncthreads();
    return sb[0] + sb[1] + sb[2] + sb[3];
}

__device__ __forceinline__ void dma16(const void* g, void* l) {
    __builtin_amdgcn_global_load_lds(
        (const __attribute__((address_space(1))) unsigned int*)g,
        (__attribute__((address_space(3))) unsigned int*)l, 16, 0, 0);
}

// expand 8 adjacency bits (starting at bit sh of w32) to bf16 0/1
__device__ __forceinline__ bf16x8 bits2bf(unsigned int w32, int sh) {
    unsigned int m = w32 >> sh;
    bf16x8 r;
#pragma unroll
    for (int j = 0; j < 8; ++j)
        r[j] = (m & (1u << j)) ? (short)0x3F80 : (short)0;
    return r;
}

// K0: ballot-pack. One wave per row: 64 dense 4B loads -> __ballot -> uint64.
// Also folds the EXACT f32 rowsum[i] = sum_k adj[i][k]*wexp[k] (wave-reduced).
// Pure HBM stream: 256 B read + 8 B write per wave-iteration, no LDS/barriers.
__global__ void k_pack(const int* __restrict__ adj, const float* __restrict__ wexp,
                       unsigned long long* __restrict__ pack64, float* __restrict__ rowsum) {
    const int l = threadIdx.x & 63;
    const int row = blockIdx.x * 4 + (threadIdx.x >> 6);
    const int* arow = adj + (size_t)row * N_ROWS;
    float rs = 0.f;
#pragma unroll 4
    for (int it = 0; it < 128; ++it) {
        int a = arow[it * 64 + l];
        float w = wexp[it * 64 + l];
        unsigned long long m = __ballot(a != 0);
        rs += a ? w : 0.f;
        if (l == 0) pack64[(size_t)row * 128 + it] = m;
    }
#pragma unroll
    for (int off = 32; off; off >>= 1) rs += __shfl_xor(rs, off);
    if (l == 0) rowsum[row] = rs;
}

// K1: M2 row k (f32) -> M2T hi/lo bf16 split [j][k]; v[k] = sum_j M2[k][j]*a2[j]
__global__ void k_M2v(const float* __restrict__ Wg, const float* __restrict__ Wa,
                      const float* __restrict__ aatt,
                      unsigned short* __restrict__ M2Thi, unsigned short* __restrict__ M2Tlo,
                      float* __restrict__ v) {
    __shared__ float sb[4];
    int k = blockIdx.x, t = threadIdx.x;
    float acc = 0.f;
#pragma unroll 8
    for (int m = 0; m < 255; ++m)
        acc += Wg[k * 255 + m] * Wa[(m + 1) * 256 + t];
    unsigned short hi = f2bf(acc);
    unsigned short lo = f2bf(acc - bf2f(hi));
    M2Thi[t * 256 + k] = hi;
    M2Tlo[t * 256 + k] = lo;
    if (k == 0) { M2Thi[t * 256 + 255] = 0; M2Tlo[t * 256 + 255] = 0; }
    float s = breduce_sum256(acc * aatt[256 + t], sb);
    if (t == 0) v[k] = s;
}

// K2: per-row logmap0 + c = logx.v -> wexp (f32); write w-scaled logx hi/lo bf16 (k-shifted)
__global__ void k_logw(const float* __restrict__ x, const float* __restrict__ v,
                       float* __restrict__ wexp,
                       unsigned short* __restrict__ Awhi, unsigned short* __restrict__ Awlo) {
    __shared__ float sb[4];
    int i0 = blockIdx.x * 8, t = threadIdx.x;
    float vv = (t >= 1) ? v[t - 1] : 0.f;
#pragma unroll
    for (int r = 0; r < 8; ++r) {
        float xv = x[(size_t)(i0 + r) * D + t];
        float yv = (t >= 1) ? xv : 0.f;
        float ss = breduce_sum256(yv * yv, sb);
        float x0 = x[(size_t)(i0 + r) * D];
        float coef = acoshf(fmaxf(x0, 1.f + 1e-7f)) / fmaxf(sqrtf(ss), 1e-15f);
        float lg = coef * yv;                 // logx[i][t]
        float c = breduce_sum256(lg * vv, sb);
        float w = expf(c - MSHIFT);
        if (t == r) wexp[i0 + r] = w;
        float aw = w * lg;
        unsigned short hi = f2bf(aw);
        unsigned short lo = f2bf(aw - bf2f(hi));
        int kd = (t == 0) ? 255 : (t - 1);    // Aw[i][k] = w*logx[i][k+1], pad k=255 -> 0
        Awhi[(size_t)(i0 + r) * 256 + kd] = hi;
        Awlo[(size_t)(i0 + r) * 256 + kd] = lo;
    }
}

// K3: GT[c][i] = sum_k M2T[c][k] * Aw[i][k]  (3-term hi/lo MFMA). 512 thr, 64 i-cols/block.
__global__ void __launch_bounds__(512)
k_hGT(const unsigned short* __restrict__ M2Thi, const unsigned short* __restrict__ M2Tlo,
      const unsigned short* __restrict__ Awhi, const unsigned short* __restrict__ Awlo,
      unsigned short* __restrict__ GT) {
    __shared__ __align__(16) char ahi[32768], alo[32768], bhi[8192], blo[8192];
    const int tid = threadIdx.x;
    const int w = tid >> 6, l = tid & 63;
    const int lr = l & 15, lq = l >> 4;
    const int i0 = blockIdx.x * 64;
    const int gs = (l & 7) ^ (l >> 3);

    const unsigned short* srcAhi[4];
    const unsigned short* srcAlo[4];
#pragma unroll
    for (int i = 0; i < 4; ++i) {
        int rowA = (w * 4 + i) * 8 + (l >> 3);
        srcAhi[i] = M2Thi + rowA * 256 + gs * 8;
        srcAlo[i] = M2Tlo + rowA * 256 + gs * 8;
    }
    int rowB = w * 8 + (l >> 3);
    const unsigned short* srcBhi = Awhi + (size_t)(i0 + rowB) * 256 + gs * 8;
    const unsigned short* srcBlo = Awlo + (size_t)(i0 + rowB) * 256 + gs * 8;

    f32x4 zero4 = {0.f, 0.f, 0.f, 0.f};
    f32x4 acc[2][4];
#pragma unroll
    for (int m = 0; m < 2; ++m)
#pragma unroll
        for (int n = 0; n < 4; ++n) acc[m][n] = zero4;

    for (int t = 0; t < 4; ++t) {
        if (t) __syncthreads();
#pragma unroll
        for (int i = 0; i < 4; ++i) {
            dma16(srcAhi[i] + t * 64, ahi + (w * 4 + i) * 1024);
            dma16(srcAlo[i] + t * 64, alo + (w * 4 + i) * 1024);
        }
        dma16(srcBhi + t * 64, bhi + w * 1024);
        dma16(srcBlo + t * 64, blo + w * 1024);
        asm volatile("s_waitcnt vmcnt(0)" ::: "memory");
        __syncthreads();
#pragma unroll
        for (int ks = 0; ks < 2; ++ks) {
            const int g = ((ks * 4 + lq) ^ (lr & 7)) * 16;
            bf16x8 afh[2], afl[2];
#pragma unroll
            for (int m = 0; m < 2; ++m) {
                int row = w * 32 + m * 16 + lr;
                afh[m] = *(const bf16x8*)(ahi + row * 128 + g);
                afl[m] = *(const bf16x8*)(alo + row * 128 + g);
            }
#pragma unroll
            for (int n = 0; n < 4; ++n) {
                int rb = n * 16 + lr;
                bf16x8 bfh = *(const bf16x8*)(bhi + rb * 128 + g);
                bf16x8 bfl = *(const bf16x8*)(blo + rb * 128 + g);
#pragma unroll
                for (int m = 0; m < 2; ++m) {
                    acc[m][n] = __builtin_amdgcn_mfma_f32_16x16x32_bf16(afh[m], bfh, acc[m][n], 0, 0, 0);
                    acc[m][n] = __builtin_amdgcn_mfma_f32_16x16x32_bf16(afh[m], bfl, acc[m][n], 0, 0, 0);
                    acc[m][n] = __builtin_amdgcn_mfma_f32_16x16x32_bf16(afl[m], bfh, acc[m][n], 0, 0, 0);
                }
            }
        }
    }
#pragma unroll
    for (int m = 0; m < 2; ++m)
#pragma unroll
        for (int n = 0; n < 4; ++n)
#pragma unroll
            for (int vv = 0; vv < 4; ++vv) {
                int c = w * 32 + m * 16 + lq * 4 + vv;
                GT[(size_t)c * N_ROWS + i0 + n * 16 + lr] = f2bf(acc[m][n][vv]);
            }
}

// K4: masked GEMM from bit-mask. BM=256, BN=256, BK=32, NKB=8. 512 thr (8 waves, 4m x 2n).
// A: block's whole 256-row x 1024-k bit slice (32 KB, pad-36) staged ONCE.
// B: 16 KB/step from XCD-pinned L2 GT slice; triple-buffer, stage(t+2) after
// barrier, counted vmcnt(2) (2 dma/wave per stage). No per-step A traffic.
__global__ void __launch_bounds__(512)
k_attbits(const unsigned int* __restrict__ pack32, const unsigned short* __restrict__ GT,
          float* __restrict__ part) {
    __shared__ __align__(16) unsigned int bitlds[256 * 36];  // cols 0..31 used
    __shared__ __align__(16) char bufB[3][16384];            // 256 cols x 32 bf16
    const int tid = threadIdx.x;
    const int kb = blockIdx.x & 7;         // XCD-pinned GT k-slice
    const int rb = blockIdx.x >> 3;        // 0..31
    const int i0 = rb * 256;
    const int kbeg = kb * KRANGE;
    const int w = tid >> 6, l = tid & 63;
    const int lr = l & 15, lq = l >> 4;
    const int wm = w >> 1, wn = w & 1;     // 4 row-groups x 2 col-groups

    // ---- bits prologue: 32 KB coalesced (8 lanes x 16B per row)
    {
        const int rloc = tid >> 3, gb = tid & 7;
#pragma unroll
        for (int p = 0; p < 4; ++p) {
            uint4 vb = *(const uint4*)(pack32 + (size_t)(i0 + p * 64 + rloc) * 256 + kb * 32 + gb * 4);
            *(uint4*)(bitlds + (p * 64 + rloc) * 36 + gb * 4) = vb;
        }
    }

    // ---- B dma sources (pre-swizzled granule; 2 insts/wave)
    const int col4 = l >> 2, gB = ((l & 3) ^ (col4 & 3)) * 8;
    const unsigned short* srcB[2];
#pragma unroll
    for (int i = 0; i < 2; ++i) {
        int b = w * 2 + i;
        srcB[i] = GT + (size_t)(b * 16 + col4) * N_ROWS + kbeg + gB;
    }
#define STAGEB(T_, BI_) do {                                           \
        _Pragma("unroll")                                              \
        for (int i_ = 0; i_ < 2; ++i_)                                 \
            dma16(srcB[i_] + (T_) * 32, bufB[BI_] + (w * 2 + i_) * 1024); \
    } while (0)

    f32x4 zero4 = {0.f, 0.f, 0.f, 0.f};
    f32x4 acc[4][8];
#pragma unroll
    for (int m = 0; m < 4; ++m)
#pragma unroll
        for (int n = 0; n < 8; ++n) acc[m][n] = zero4;

    // prologue: stage B(0), B(1); __syncthreads drains DMA + publishes bits
    STAGEB(0, 0);
    STAGEB(1, 1);
    __syncthreads();

    int cb = 0;
    for (int t = 0; t < NSTEP; ++t) {
        if (t > 0) {
            if (t < NSTEP - 1) asm volatile("s_waitcnt vmcnt(2)" ::: "memory");
            else               asm volatile("s_waitcnt vmcnt(0)" ::: "memory");
            __builtin_amdgcn_sched_barrier(0);
            __builtin_amdgcn_s_barrier();
            __builtin_amdgcn_sched_barrier(0);
        }
        if (t + 2 < NSTEP) {
            int nb2 = (cb >= 1) ? cb - 1 : cb + 2;   // (t+2)%3
            STAGEB(t + 2, nb2);
        }
        const char* bB = bufB[cb];

        bf16x8 af[4];
#pragma unroll
        for (int m = 0; m < 4; ++m) {
            int row = wm * 64 + m * 16 + lr;
            unsigned int bits = bitlds[row * 36 + t];
            af[m] = bits2bf(bits, lq * 8);
        }
#pragma unroll
        for (int n = 0; n < 8; ++n) {
            int col = wn * 128 + n * 16 + lr;
            bf16x8 bf = *(const bf16x8*)(bB + col * 64 + ((lq ^ (lr & 3)) << 4));
#pragma unroll
            for (int m = 0; m < 4; ++m)
                acc[m][n] = __builtin_amdgcn_mfma_f32_16x16x32_bf16(af[m], bf, acc[m][n], 0, 0, 0);
        }
        cb = (cb == 2) ? 0 : cb + 1;
    }
#undef STAGEB

    // C write (layout: col=lane&15, row=(lane>>4)*4+reg); nontemporal
    float* pbase = part + (size_t)kb * N_ROWS * D;
#pragma unroll
    for (int m = 0; m < 4; ++m)
#pragma unroll
        for (int n = 0; n < 8; ++n) {
            int orow = i0 + wm * 64 + m * 16 + lq * 4;
            int ocol = wn * 128 + n * 16 + lr;
            float* op = pbase + (size_t)orow * D + ocol;
#pragma unroll
            for (int vv = 0; vv < 4; ++vv)
                __builtin_nontemporal_store(acc[m][n][vv], op + (size_t)vv * D);
        }
}

// K5: split-K reduce + epilogue (divide, elu, proj, logmap0, sigmoid, expmap0)
__global__ void k_final3(const float* __restrict__ part, const float* __restrict__ rowsum,
                         float* __restrict__ out) {
    __shared__ float sb[4];
    int row = blockIdx.x, t = threadIdx.x;
    float raw = 0.f;
#pragma unroll
    for (int kbi = 0; kbi < NKB; ++kbi)
        raw += __builtin_nontemporal_load(&part[((size_t)kbi * N_ROWS + row) * D + t]);
    float rs = rowsum[row];
    float hp = raw / rs;
    float ey = 0.f;
    if (t >= 1) ey = (hp > 0.f) ? hp : expm1f(hp);
    float ss = breduce_sum256(ey * ey, sb);
    float x0 = sqrtf(1.f + ss);
    float th = fmaxf(x0, 1.f + 1e-7f);
    float al = acoshf(th);
    float yn = fmaxf(sqrtf(ss), 1e-15f);
    float u = (t >= 1) ? (al * ey / yn) : 0.f;
    float s = 1.f / (1.f + expf(-u));
    float s2 = (t >= 1) ? s * s : 0.f;
    float ssn = breduce_sum256(s2, sb);
    float xn = fmaxf(sqrtf(ssn), 1e-15f);
    float sh = sinhf(xn);
    float yf = (t >= 1) ? (sh * s / xn) : 0.f;
    float sy = breduce_sum256(yf * yf, sb);
    float res = (t == 0) ? sqrtf(1.f + sy) : yf;
    out[(size_t)row * D + t] = res;
}

extern "C" void kernel_launch(void* const* d_in, const int* in_sizes, int n_in,
                              void* d_out, int out_size, void* d_ws, size_t ws_size,
                              hipStream_t stream) {
    const float* x    = (const float*)d_in[0];
    const int*   adj  = (const int*)d_in[1];
    const float* Wg   = (const float*)d_in[3];
    const float* Wa   = (const float*)d_in[4];
    const float* aatt = (const float*)d_in[5];
    float* out = (float*)d_out;

    char* wsb = (char*)d_ws;
    unsigned short* M2Thi  = (unsigned short*)(wsb);              // 128 KB
    unsigned short* M2Tlo  = (unsigned short*)(wsb + 0x0020000);  // 128 KB
    float*          v      = (float*)(wsb + 0x0040000);           // 1 KB
    float*          wexp   = (float*)(wsb + 0x0048000);           // 32 KB
    float*          rowsum = (float*)(wsb + 0x0050000);           // 32 KB
    unsigned short* Awhi   = (unsigned short*)(wsb + 0x0100000);  // 4 MB
    unsigned short* Awlo   = (unsigned short*)(wsb + 0x0500000);  // 4 MB
    unsigned short* GT     = (unsigned short*)(wsb + 0x0900000);  // 4 MB
    float*          part   = (float*)(wsb + 0x1000000);           // 64 MB (NKB x 8 MB)
    unsigned long long* pack64 = (unsigned long long*)(wsb + 0x5000000); // 8 MB

    k_M2v<<<255, 256, 0, stream>>>(Wg, Wa, aatt, M2Thi, M2Tlo, v);
    k_logw<<<N_ROWS / 8, 256, 0, stream>>>(x, v, wexp, Awhi, Awlo);
    k_pack<<<N_ROWS / 4, 256, 0, stream>>>(adj, wexp, pack64, rowsum);
    k_hGT<<<N_ROWS / 64, 512, 0, stream>>>(M2Thi, M2Tlo, Awhi, Awlo, GT);
    k_attbits<<<32 * NKB, 512, 0, stream>>>((const unsigned int*)pack64, GT, part);
    k_final3<<<N_ROWS, 256, 0, stream>>>(part, rowsum, out);
}

// Round 15
// 183.857 us; speedup vs baseline: 1.2365x; 1.2365x over previous
//
#include <hip/hip_runtime.h>
#include <hip/hip_bf16.h>
#include <math.h>

typedef __attribute__((ext_vector_type(4))) float f32x4;
typedef __attribute__((ext_vector_type(8))) short bf16x8;
typedef __attribute__((ext_vector_type(2))) unsigned long long u64x2;

#define N_ROWS 8192
#define D 256
#define MSHIFT 16.0f
#define NKB 8
#define KRANGE (N_ROWS / NKB)     // 1024
#define NSTEP (KRANGE / 32)       // 32 (BK=32)

__device__ __forceinline__ unsigned short f2bf(float f) {
    unsigned int u = __float_as_uint(f);
    unsigned int r = u + 0x7FFFu + ((u >> 16) & 1u);
    return (unsigned short)(r >> 16);
}
__device__ __forceinline__ float bf2f(unsigned short h) {
    return __uint_as_float(((unsigned int)h) << 16);
}

__device__ __forceinline__ float breduce_sum256(float v, float* sb) {
#pragma unroll
    for (int off = 32; off; off >>= 1) v += __shfl_down(v, off);
    int wid = threadIdx.x >> 6;
    __syncthreads();
    if ((threadIdx.x & 63) == 0) sb[wid] = v;
    __syncthreads();
    return sb[0] + sb[1] + sb[2] + sb[3];
}

__device__ __forceinline__ void dma16(const void* g, void* l) {
    __builtin_amdgcn_global_load_lds(
        (const __attribute__((address_space(1))) unsigned int*)g,
        (__attribute__((address_space(3))) unsigned int*)l, 16, 0, 0);
}

// expand 8 adjacency bits (starting at bit sh of w32) to bf16 0/1
__device__ __forceinline__ bf16x8 bits2bf(unsigned int w32, int sh) {
    unsigned int m = w32 >> sh;
    bf16x8 r;
#pragma unroll
    for (int j = 0; j < 8; ++j)
        r[j] = (m & (1u << j)) ? (short)0x3F80 : (short)0;
    return r;
}

// K0: ballot-pack with BATCHED loads (8 independent loads in flight before the
// convergent ballots -- defeats the ballot-blocks-load-hoisting serialization).
// One wave per row. Also folds exact f32 rowsum[i] = sum_k adj[i][k]*wexp[k].
__global__ void k_pack(const int* __restrict__ adj, const float* __restrict__ wexp,
                       unsigned long long* __restrict__ pack64, float* __restrict__ rowsum) {
    const int l = threadIdx.x & 63;
    const int row = blockIdx.x * 4 + (threadIdx.x >> 6);
    const int* arow = adj + (size_t)row * N_ROWS;
    float rs = 0.f;
    for (int g = 0; g < 16; ++g) {
        int a[8];
        float w[8];
#pragma unroll
        for (int i = 0; i < 8; ++i) a[i] = arow[(g * 8 + i) * 64 + l];
#pragma unroll
        for (int i = 0; i < 8; ++i) w[i] = wexp[(g * 8 + i) * 64 + l];
        __builtin_amdgcn_sched_barrier(0);   // keep all 16 loads issued before ballots
        unsigned long long m[8];
#pragma unroll
        for (int i = 0; i < 8; ++i) {
            m[i] = __ballot(a[i] != 0);
            rs += a[i] ? w[i] : 0.f;
        }
        if (l == 0) {
#pragma unroll
            for (int i = 0; i < 4; ++i) {
                u64x2 st = {m[2 * i], m[2 * i + 1]};
                *(u64x2*)(&pack64[(size_t)row * 128 + g * 8 + 2 * i]) = st;
            }
        }
    }
#pragma unroll
    for (int off = 32; off; off >>= 1) rs += __shfl_xor(rs, off);
    if (l == 0) rowsum[row] = rs;
}

// K1: M2 row k (f32) -> M2T hi/lo bf16 split [j][k]; v[k] = sum_j M2[k][j]*a2[j]
__global__ void k_M2v(const float* __restrict__ Wg, const float* __restrict__ Wa,
                      const float* __restrict__ aatt,
                      unsigned short* __restrict__ M2Thi, unsigned short* __restrict__ M2Tlo,
                      float* __restrict__ v) {
    __shared__ float sb[4];
    int k = blockIdx.x, t = threadIdx.x;
    float acc = 0.f;
#pragma unroll 8
    for (int m = 0; m < 255; ++m)
        acc += Wg[k * 255 + m] * Wa[(m + 1) * 256 + t];
    unsigned short hi = f2bf(acc);
    unsigned short lo = f2bf(acc - bf2f(hi));
    M2Thi[t * 256 + k] = hi;
    M2Tlo[t * 256 + k] = lo;
    if (k == 0) { M2Thi[t * 256 + 255] = 0; M2Tlo[t * 256 + 255] = 0; }
    float s = breduce_sum256(acc * aatt[256 + t], sb);
    if (t == 0) v[k] = s;
}

// K2: per-row logmap0 + c = logx.v -> wexp (f32); write w-scaled logx hi/lo bf16 (k-shifted)
__global__ void k_logw(const float* __restrict__ x, const float* __restrict__ v,
                       float* __restrict__ wexp,
                       unsigned short* __restrict__ Awhi, unsigned short* __restrict__ Awlo) {
    __shared__ float sb[4];
    int i0 = blockIdx.x * 8, t = threadIdx.x;
    float vv = (t >= 1) ? v[t - 1] : 0.f;
#pragma unroll
    for (int r = 0; r < 8; ++r) {
        float xv = x[(size_t)(i0 + r) * D + t];
        float yv = (t >= 1) ? xv : 0.f;
        float ss = breduce_sum256(yv * yv, sb);
        float x0 = x[(size_t)(i0 + r) * D];
        float coef = acoshf(fmaxf(x0, 1.f + 1e-7f)) / fmaxf(sqrtf(ss), 1e-15f);
        float lg = coef * yv;                 // logx[i][t]
        float c = breduce_sum256(lg * vv, sb);
        float w = expf(c - MSHIFT);
        if (t == r) wexp[i0 + r] = w;
        float aw = w * lg;
        unsigned short hi = f2bf(aw);
        unsigned short lo = f2bf(aw - bf2f(hi));
        int kd = (t == 0) ? 255 : (t - 1);    // Aw[i][k] = w*logx[i][k+1], pad k=255 -> 0
        Awhi[(size_t)(i0 + r) * 256 + kd] = hi;
        Awlo[(size_t)(i0 + r) * 256 + kd] = lo;
    }
}

// K3: GT[c][i] = sum_k M2T[c][k] * Aw[i][k]  (3-term hi/lo MFMA). 512 thr, 64 i-cols/block.
__global__ void __launch_bounds__(512)
k_hGT(const unsigned short* __restrict__ M2Thi, const unsigned short* __restrict__ M2Tlo,
      const unsigned short* __restrict__ Awhi, const unsigned short* __restrict__ Awlo,
      unsigned short* __restrict__ GT) {
    __shared__ __align__(16) char ahi[32768], alo[32768], bhi[8192], blo[8192];
    const int tid = threadIdx.x;
    const int w = tid >> 6, l = tid & 63;
    const int lr = l & 15, lq = l >> 4;
    const int i0 = blockIdx.x * 64;
    const int gs = (l & 7) ^ (l >> 3);

    const unsigned short* srcAhi[4];
    const unsigned short* srcAlo[4];
#pragma unroll
    for (int i = 0; i < 4; ++i) {
        int rowA = (w * 4 + i) * 8 + (l >> 3);
        srcAhi[i] = M2Thi + rowA * 256 + gs * 8;
        srcAlo[i] = M2Tlo + rowA * 256 + gs * 8;
    }
    int rowB = w * 8 + (l >> 3);
    const unsigned short* srcBhi = Awhi + (size_t)(i0 + rowB) * 256 + gs * 8;
    const unsigned short* srcBlo = Awlo + (size_t)(i0 + rowB) * 256 + gs * 8;

    f32x4 zero4 = {0.f, 0.f, 0.f, 0.f};
    f32x4 acc[2][4];
#pragma unroll
    for (int m = 0; m < 2; ++m)
#pragma unroll
        for (int n = 0; n < 4; ++n) acc[m][n] = zero4;

    for (int t = 0; t < 4; ++t) {
        if (t) __syncthreads();
#pragma unroll
        for (int i = 0; i < 4; ++i) {
            dma16(srcAhi[i] + t * 64, ahi + (w * 4 + i) * 1024);
            dma16(srcAlo[i] + t * 64, alo + (w * 4 + i) * 1024);
        }
        dma16(srcBhi + t * 64, bhi + w * 1024);
        dma16(srcBlo + t * 64, blo + w * 1024);
        asm volatile("s_waitcnt vmcnt(0)" ::: "memory");
        __syncthreads();
#pragma unroll
        for (int ks = 0; ks < 2; ++ks) {
            const int g = ((ks * 4 + lq) ^ (lr & 7)) * 16;
            bf16x8 afh[2], afl[2];
#pragma unroll
            for (int m = 0; m < 2; ++m) {
                int row = w * 32 + m * 16 + lr;
                afh[m] = *(const bf16x8*)(ahi + row * 128 + g);
                afl[m] = *(const bf16x8*)(alo + row * 128 + g);
            }
#pragma unroll
            for (int n = 0; n < 4; ++n) {
                int rb = n * 16 + lr;
                bf16x8 bfh = *(const bf16x8*)(bhi + rb * 128 + g);
                bf16x8 bfl = *(const bf16x8*)(blo + rb * 128 + g);
#pragma unroll
                for (int m = 0; m < 2; ++m) {
                    acc[m][n] = __builtin_amdgcn_mfma_f32_16x16x32_bf16(afh[m], bfh, acc[m][n], 0, 0, 0);
                    acc[m][n] = __builtin_amdgcn_mfma_f32_16x16x32_bf16(afh[m], bfl, acc[m][n], 0, 0, 0);
                    acc[m][n] = __builtin_amdgcn_mfma_f32_16x16x32_bf16(afl[m], bfh, acc[m][n], 0, 0, 0);
                }
            }
        }
    }
#pragma unroll
    for (int m = 0; m < 2; ++m)
#pragma unroll
        for (int n = 0; n < 4; ++n)
#pragma unroll
            for (int vv = 0; vv < 4; ++vv) {
                int c = w * 32 + m * 16 + lq * 4 + vv;
                GT[(size_t)c * N_ROWS + i0 + n * 16 + lr] = f2bf(acc[m][n][vv]);
            }
}

// K4: masked GEMM from bit-mask. BM=256, BN=256, BK=32, NKB=8. 512 thr (8 waves, 4m x 2n).
// A: block's whole 256-row x 1024-k bit slice (32 KB, pad-36) staged ONCE.
// B: 16 KB/step from XCD-pinned L2 GT slice; triple-buffer, stage(t+2) after
// barrier, counted vmcnt(2). No per-step A traffic.
__global__ void __launch_bounds__(512)
k_attbits(const unsigned int* __restrict__ pack32, const unsigned short* __restrict__ GT,
          float* __restrict__ part) {
    __shared__ __align__(16) unsigned int bitlds[256 * 36];  // cols 0..31 used
    __shared__ __align__(16) char bufB[3][16384];            // 256 cols x 32 bf16
    const int tid = threadIdx.x;
    const int kb = blockIdx.x & 7;         // XCD-pinned GT k-slice
    const int rb = blockIdx.x >> 3;        // 0..31
    const int i0 = rb * 256;
    const int kbeg = kb * KRANGE;
    const int w = tid >> 6, l = tid & 63;
    const int lr = l & 15, lq = l >> 4;
    const int wm = w >> 1, wn = w & 1;     // 4 row-groups x 2 col-groups

    // ---- bits prologue: 32 KB coalesced (8 lanes x 16B per row)
    {
        const int rloc = tid >> 3, gb = tid & 7;
#pragma unroll
        for (int p = 0; p < 4; ++p) {
            uint4 vb = *(const uint4*)(pack32 + (size_t)(i0 + p * 64 + rloc) * 256 + kb * 32 + gb * 4);
            *(uint4*)(bitlds + (p * 64 + rloc) * 36 + gb * 4) = vb;
        }
    }

    // ---- B dma sources (pre-swizzled granule; 2 insts/wave)
    const int col4 = l >> 2, gB = ((l & 3) ^ (col4 & 3)) * 8;
    const unsigned short* srcB[2];
#pragma unroll
    for (int i = 0; i < 2; ++i) {
        int b = w * 2 + i;
        srcB[i] = GT + (size_t)(b * 16 + col4) * N_ROWS + kbeg + gB;
    }
#define STAGEB(T_, BI_) do {                                           \
        _Pragma("unroll")                                              \
        for (int i_ = 0; i_ < 2; ++i_)                                 \
            dma16(srcB[i_] + (T_) * 32, bufB[BI_] + (w * 2 + i_) * 1024); \
    } while (0)

    f32x4 zero4 = {0.f, 0.f, 0.f, 0.f};
    f32x4 acc[4][8];
#pragma unroll
    for (int m = 0; m < 4; ++m)
#pragma unroll
        for (int n = 0; n < 8; ++n) acc[m][n] = zero4;

    // prologue: stage B(0), B(1); __syncthreads drains DMA + publishes bits
    STAGEB(0, 0);
    STAGEB(1, 1);
    __syncthreads();

    int cb = 0;
    for (int t = 0; t < NSTEP; ++t) {
        if (t > 0) {
            if (t < NSTEP - 1) asm volatile("s_waitcnt vmcnt(2)" ::: "memory");
            else               asm volatile("s_waitcnt vmcnt(0)" ::: "memory");
            __builtin_amdgcn_sched_barrier(0);
            __builtin_amdgcn_s_barrier();
            __builtin_amdgcn_sched_barrier(0);
        }
        if (t + 2 < NSTEP) {
            int nb2 = (cb >= 1) ? cb - 1 : cb + 2;   // (t+2)%3
            STAGEB(t + 2, nb2);
        }
        const char* bB = bufB[cb];

        bf16x8 af[4];
#pragma unroll
        for (int m = 0; m < 4; ++m) {
            int row = wm * 64 + m * 16 + lr;
            unsigned int bits = bitlds[row * 36 + t];
            af[m] = bits2bf(bits, lq * 8);
        }
#pragma unroll
        for (int n = 0; n < 8; ++n) {
            int col = wn * 128 + n * 16 + lr;
            bf16x8 bf = *(const bf16x8*)(bB + col * 64 + ((lq ^ (lr & 3)) << 4));
#pragma unroll
            for (int m = 0; m < 4; ++m)
                acc[m][n] = __builtin_amdgcn_mfma_f32_16x16x32_bf16(af[m], bf, acc[m][n], 0, 0, 0);
        }
        cb = (cb == 2) ? 0 : cb + 1;
    }
#undef STAGEB

    // C write (layout: col=lane&15, row=(lane>>4)*4+reg); nontemporal
    float* pbase = part + (size_t)kb * N_ROWS * D;
#pragma unroll
    for (int m = 0; m < 4; ++m)
#pragma unroll
        for (int n = 0; n < 8; ++n) {
            int orow = i0 + wm * 64 + m * 16 + lq * 4;
            int ocol = wn * 128 + n * 16 + lr;
            float* op = pbase + (size_t)orow * D + ocol;
#pragma unroll
            for (int vv = 0; vv < 4; ++vv)
                __builtin_nontemporal_store(acc[m][n][vv], op + (size_t)vv * D);
        }
}

// K5: split-K reduce + epilogue (divide, elu, proj, logmap0, sigmoid, expmap0)
__global__ void k_final3(const float* __restrict__ part, const float* __restrict__ rowsum,
                         float* __restrict__ out) {
    __shared__ float sb[4];
    int row = blockIdx.x, t = threadIdx.x;
    float raw = 0.f;
#pragma unroll
    for (int kbi = 0; kbi < NKB; ++kbi)
        raw += __builtin_nontemporal_load(&part[((size_t)kbi * N_ROWS + row) * D + t]);
    float rs = rowsum[row];
    float hp = raw / rs;
    float ey = 0.f;
    if (t >= 1) ey = (hp > 0.f) ? hp : expm1f(hp);
    float ss = breduce_sum256(ey * ey, sb);
    float x0 = sqrtf(1.f + ss);
    float th = fmaxf(x0, 1.f + 1e-7f);
    float al = acoshf(th);
    float yn = fmaxf(sqrtf(ss), 1e-15f);
    float u = (t >= 1) ? (al * ey / yn) : 0.f;
    float s = 1.f / (1.f + expf(-u));
    float s2 = (t >= 1) ? s * s : 0.f;
    float ssn = breduce_sum256(s2, sb);
    float xn = fmaxf(sqrtf(ssn), 1e-15f);
    float sh = sinhf(xn);
    float yf = (t >= 1) ? (sh * s / xn) : 0.f;
    float sy = breduce_sum256(yf * yf, sb);
    float res = (t == 0) ? sqrtf(1.f + sy) : yf;
    out[(size_t)row * D + t] = res;
}

extern "C" void kernel_launch(void* const* d_in, const int* in_sizes, int n_in,
                              void* d_out, int out_size, void* d_ws, size_t ws_size,
                              hipStream_t stream) {
    const float* x    = (const float*)d_in[0];
    const int*   adj  = (const int*)d_in[1];
    const float* Wg   = (const float*)d_in[3];
    const float* Wa   = (const float*)d_in[4];
    const float* aatt = (const float*)d_in[5];
    float* out = (float*)d_out;

    char* wsb = (char*)d_ws;
    unsigned short* M2Thi  = (unsigned short*)(wsb);              // 128 KB
    unsigned short* M2Tlo  = (unsigned short*)(wsb + 0x0020000);  // 128 KB
    float*          v      = (float*)(wsb + 0x0040000);           // 1 KB
    float*          wexp   = (float*)(wsb + 0x0048000);           // 32 KB
    float*          rowsum = (float*)(wsb + 0x0050000);           // 32 KB
    unsigned short* Awhi   = (unsigned short*)(wsb + 0x0100000);  // 4 MB
    unsigned short* Awlo   = (unsigned short*)(wsb + 0x0500000);  // 4 MB
    unsigned short* GT     = (unsigned short*)(wsb + 0x0900000);  // 4 MB
    float*          part   = (float*)(wsb + 0x1000000);           // 64 MB (NKB x 8 MB)
    unsigned long long* pack64 = (unsigned long long*)(wsb + 0x5000000); // 8 MB

    k_M2v<<<255, 256, 0, stream>>>(Wg, Wa, aatt, M2Thi, M2Tlo, v);
    k_logw<<<N_ROWS / 8, 256, 0, stream>>>(x, v, wexp, Awhi, Awlo);
    k_pack<<<N_ROWS / 4, 256, 0, stream>>>(adj, wexp, pack64, rowsum);
    k_hGT<<<N_ROWS / 64, 512, 0, stream>>>(M2Thi, M2Tlo, Awhi, Awlo, GT);
    k_attbits<<<32 * NKB, 512, 0, stream>>>((const unsigned int*)pack64, GT, part);
    k_final3<<<N_ROWS, 256, 0, stream>>>(part, rowsum, out);
}

// Round 16
// 183.557 us; speedup vs baseline: 1.2385x; 1.0016x over previous
//
#include <hip/hip_runtime.h>
#include <hip/hip_bf16.h>
#include <math.h>

typedef __attribute__((ext_vector_type(4))) float f32x4;
typedef __attribute__((ext_vector_type(8))) short bf16x8;
typedef __attribute__((ext_vector_type(2))) unsigned long long u64x2;

#define N_ROWS 8192
#define D 256
#define MSHIFT 16.0f
#define NKB 8
#define KRANGE (N_ROWS / NKB)     // 1024
#define NSTEP (KRANGE / 32)       // 32 (BK=32)

__device__ __forceinline__ unsigned short f2bf(float f) {
    unsigned int u = __float_as_uint(f);
    unsigned int r = u + 0x7FFFu + ((u >> 16) & 1u);
    return (unsigned short)(r >> 16);
}
__device__ __forceinline__ float bf2f(unsigned short h) {
    return __uint_as_float(((unsigned int)h) << 16);
}

__device__ __forceinline__ float breduce_sum256(float v, float* sb) {
#pragma unroll
    for (int off = 32; off; off >>= 1) v += __shfl_down(v, off);
    int wid = threadIdx.x >> 6;
    __syncthreads();
    if ((threadIdx.x & 63) == 0) sb[wid] = v;
    __syncthreads();
    return sb[0] + sb[1] + sb[2] + sb[3];
}

__device__ __forceinline__ void dma16(const void* g, void* l) {
    __builtin_amdgcn_global_load_lds(
        (const __attribute__((address_space(1))) unsigned int*)g,
        (__attribute__((address_space(3))) unsigned int*)l, 16, 0, 0);
}

// expand 8 adjacency bits (starting at bit sh of w32) to bf16 0/1
__device__ __forceinline__ bf16x8 bits2bf(unsigned int w32, int sh) {
    unsigned int m = w32 >> sh;
    bf16x8 r;
#pragma unroll
    for (int j = 0; j < 8; ++j)
        r[j] = (m & (1u << j)) ? (short)0x3F80 : (short)0;
    return r;
}

// K0: ballot-pack, wexp read from LDS (halves the global load-path bytes).
// 8 rows/block (512 thr, wave per row); 16 batched adj loads in flight before
// the convergent ballots. Folds exact f32 rowsum[i] = sum_k adj[i][k]*wexp[k].
__global__ void __launch_bounds__(512)
k_pack(const int* __restrict__ adj, const float* __restrict__ wexp,
       unsigned long long* __restrict__ pack64, float* __restrict__ rowsum) {
    __shared__ float wlds[N_ROWS];
    const int tid = threadIdx.x;
    const int l = tid & 63;
    const int row = blockIdx.x * 8 + (tid >> 6);
    // stage wexp (32 KB) once per block, coalesced float4
#pragma unroll
    for (int i = 0; i < 4; ++i) {
        float4 v4 = *(const float4*)(wexp + (i * 512 + tid) * 4);
        *(float4*)(&wlds[(i * 512 + tid) * 4]) = v4;
    }
    __syncthreads();

    const int* arow = adj + (size_t)row * N_ROWS;
    float rs = 0.f;
    for (int g = 0; g < 8; ++g) {
        int a[16];
#pragma unroll
        for (int i = 0; i < 16; ++i) a[i] = arow[(g * 16 + i) * 64 + l];
        __builtin_amdgcn_sched_barrier(0);   // keep all 16 loads issued before ballots
        unsigned long long m[16];
#pragma unroll
        for (int i = 0; i < 16; ++i) {
            m[i] = __ballot(a[i] != 0);
            rs += a[i] ? wlds[(g * 16 + i) * 64 + l] : 0.f;
        }
        if (l == 0) {
#pragma unroll
            for (int i = 0; i < 8; ++i) {
                u64x2 st = {m[2 * i], m[2 * i + 1]};
                *(u64x2*)(&pack64[(size_t)row * 128 + g * 16 + 2 * i]) = st;
            }
        }
    }
#pragma unroll
    for (int off = 32; off; off >>= 1) rs += __shfl_xor(rs, off);
    if (l == 0) rowsum[row] = rs;
}

// K1: M2 row k (f32) -> M2T hi/lo bf16 split [j][k]; v[k] = sum_j M2[k][j]*a2[j]
__global__ void k_M2v(const float* __restrict__ Wg, const float* __restrict__ Wa,
                      const float* __restrict__ aatt,
                      unsigned short* __restrict__ M2Thi, unsigned short* __restrict__ M2Tlo,
                      float* __restrict__ v) {
    __shared__ float sb[4];
    int k = blockIdx.x, t = threadIdx.x;
    float acc = 0.f;
#pragma unroll 8
    for (int m = 0; m < 255; ++m)
        acc += Wg[k * 255 + m] * Wa[(m + 1) * 256 + t];
    unsigned short hi = f2bf(acc);
    unsigned short lo = f2bf(acc - bf2f(hi));
    M2Thi[t * 256 + k] = hi;
    M2Tlo[t * 256 + k] = lo;
    if (k == 0) { M2Thi[t * 256 + 255] = 0; M2Tlo[t * 256 + 255] = 0; }
    float s = breduce_sum256(acc * aatt[256 + t], sb);
    if (t == 0) v[k] = s;
}

// K2: per-row logmap0 + c = logx.v -> wexp (f32); write w-scaled logx hi/lo bf16 (k-shifted)
__global__ void k_logw(const float* __restrict__ x, const float* __restrict__ v,
                       float* __restrict__ wexp,
                       unsigned short* __restrict__ Awhi, unsigned short* __restrict__ Awlo) {
    __shared__ float sb[4];
    int i0 = blockIdx.x * 8, t = threadIdx.x;
    float vv = (t >= 1) ? v[t - 1] : 0.f;
#pragma unroll
    for (int r = 0; r < 8; ++r) {
        float xv = x[(size_t)(i0 + r) * D + t];
        float yv = (t >= 1) ? xv : 0.f;
        float ss = breduce_sum256(yv * yv, sb);
        float x0 = x[(size_t)(i0 + r) * D];
        float coef = acoshf(fmaxf(x0, 1.f + 1e-7f)) / fmaxf(sqrtf(ss), 1e-15f);
        float lg = coef * yv;                 // logx[i][t]
        float c = breduce_sum256(lg * vv, sb);
        float w = expf(c - MSHIFT);
        if (t == r) wexp[i0 + r] = w;
        float aw = w * lg;
        unsigned short hi = f2bf(aw);
        unsigned short lo = f2bf(aw - bf2f(hi));
        int kd = (t == 0) ? 255 : (t - 1);    // Aw[i][k] = w*logx[i][k+1], pad k=255 -> 0
        Awhi[(size_t)(i0 + r) * 256 + kd] = hi;
        Awlo[(size_t)(i0 + r) * 256 + kd] = lo;
    }
}

// K3: GT[c][i] = sum_k M2T[c][k] * Aw[i][k]  (3-term hi/lo MFMA). 512 thr, 64 i-cols/block.
__global__ void __launch_bounds__(512)
k_hGT(const unsigned short* __restrict__ M2Thi, const unsigned short* __restrict__ M2Tlo,
      const unsigned short* __restrict__ Awhi, const unsigned short* __restrict__ Awlo,
      unsigned short* __restrict__ GT) {
    __shared__ __align__(16) char ahi[32768], alo[32768], bhi[8192], blo[8192];
    const int tid = threadIdx.x;
    const int w = tid >> 6, l = tid & 63;
    const int lr = l & 15, lq = l >> 4;
    const int i0 = blockIdx.x * 64;
    const int gs = (l & 7) ^ (l >> 3);

    const unsigned short* srcAhi[4];
    const unsigned short* srcAlo[4];
#pragma unroll
    for (int i = 0; i < 4; ++i) {
        int rowA = (w * 4 + i) * 8 + (l >> 3);
        srcAhi[i] = M2Thi + rowA * 256 + gs * 8;
        srcAlo[i] = M2Tlo + rowA * 256 + gs * 8;
    }
    int rowB = w * 8 + (l >> 3);
    const unsigned short* srcBhi = Awhi + (size_t)(i0 + rowB) * 256 + gs * 8;
    const unsigned short* srcBlo = Awlo + (size_t)(i0 + rowB) * 256 + gs * 8;

    f32x4 zero4 = {0.f, 0.f, 0.f, 0.f};
    f32x4 acc[2][4];
#pragma unroll
    for (int m = 0; m < 2; ++m)
#pragma unroll
        for (int n = 0; n < 4; ++n) acc[m][n] = zero4;

    for (int t = 0; t < 4; ++t) {
        if (t) __syncthreads();
#pragma unroll
        for (int i = 0; i < 4; ++i) {
            dma16(srcAhi[i] + t * 64, ahi + (w * 4 + i) * 1024);
            dma16(srcAlo[i] + t * 64, alo + (w * 4 + i) * 1024);
        }
        dma16(srcBhi + t * 64, bhi + w * 1024);
        dma16(srcBlo + t * 64, blo + w * 1024);
        asm volatile("s_waitcnt vmcnt(0)" ::: "memory");
        __syncthreads();
#pragma unroll
        for (int ks = 0; ks < 2; ++ks) {
            const int g = ((ks * 4 + lq) ^ (lr & 7)) * 16;
            bf16x8 afh[2], afl[2];
#pragma unroll
            for (int m = 0; m < 2; ++m) {
                int row = w * 32 + m * 16 + lr;
                afh[m] = *(const bf16x8*)(ahi + row * 128 + g);
                afl[m] = *(const bf16x8*)(alo + row * 128 + g);
            }
#pragma unroll
            for (int n = 0; n < 4; ++n) {
                int rb = n * 16 + lr;
                bf16x8 bfh = *(const bf16x8*)(bhi + rb * 128 + g);
                bf16x8 bfl = *(const bf16x8*)(blo + rb * 128 + g);
#pragma unroll
                for (int m = 0; m < 2; ++m) {
                    acc[m][n] = __builtin_amdgcn_mfma_f32_16x16x32_bf16(afh[m], bfh, acc[m][n], 0, 0, 0);
                    acc[m][n] = __builtin_amdgcn_mfma_f32_16x16x32_bf16(afh[m], bfl, acc[m][n], 0, 0, 0);
                    acc[m][n] = __builtin_amdgcn_mfma_f32_16x16x32_bf16(afl[m], bfh, acc[m][n], 0, 0, 0);
                }
            }
        }
    }
#pragma unroll
    for (int m = 0; m < 2; ++m)
#pragma unroll
        for (int n = 0; n < 4; ++n)
#pragma unroll
            for (int vv = 0; vv < 4; ++vv) {
                int c = w * 32 + m * 16 + lq * 4 + vv;
                GT[(size_t)c * N_ROWS + i0 + n * 16 + lr] = f2bf(acc[m][n][vv]);
            }
}

// K4: masked GEMM from bit-mask. BM=256, BN=256, BK=32, NKB=8. 512 thr (8 waves, 4m x 2n).
// A: block's whole 256-row x 1024-k bit slice (32 KB, pad-36) staged ONCE.
// B: 16 KB/step from XCD-pinned L2 GT slice; triple-buffer, stage(t+2) after
// barrier, counted vmcnt(2). No per-step A traffic.
__global__ void __launch_bounds__(512)
k_attbits(const unsigned int* __restrict__ pack32, const unsigned short* __restrict__ GT,
          float* __restrict__ part) {
    __shared__ __align__(16) unsigned int bitlds[256 * 36];  // cols 0..31 used
    __shared__ __align__(16) char bufB[3][16384];            // 256 cols x 32 bf16
    const int tid = threadIdx.x;
    const int kb = blockIdx.x & 7;         // XCD-pinned GT k-slice
    const int rb = blockIdx.x >> 3;        // 0..31
    const int i0 = rb * 256;
    const int kbeg = kb * KRANGE;
    const int w = tid >> 6, l = tid & 63;
    const int lr = l & 15, lq = l >> 4;
    const int wm = w >> 1, wn = w & 1;     // 4 row-groups x 2 col-groups

    // ---- bits prologue: 32 KB coalesced (8 lanes x 16B per row)
    {
        const int rloc = tid >> 3, gb = tid & 7;
#pragma unroll
        for (int p = 0; p < 4; ++p) {
            uint4 vb = *(const uint4*)(pack32 + (size_t)(i0 + p * 64 + rloc) * 256 + kb * 32 + gb * 4);
            *(uint4*)(bitlds + (p * 64 + rloc) * 36 + gb * 4) = vb;
        }
    }

    // ---- B dma sources (pre-swizzled granule; 2 insts/wave)
    const int col4 = l >> 2, gB = ((l & 3) ^ (col4 & 3)) * 8;
    const unsigned short* srcB[2];
#pragma unroll
    for (int i = 0; i < 2; ++i) {
        int b = w * 2 + i;
        srcB[i] = GT + (size_t)(b * 16 + col4) * N_ROWS + kbeg + gB;
    }
#define STAGEB(T_, BI_) do {                                           \
        _Pragma("unroll")                                              \
        for (int i_ = 0; i_ < 2; ++i_)                                 \
            dma16(srcB[i_] + (T_) * 32, bufB[BI_] + (w * 2 + i_) * 1024); \
    } while (0)

    f32x4 zero4 = {0.f, 0.f, 0.f, 0.f};
    f32x4 acc[4][8];
#pragma unroll
    for (int m = 0; m < 4; ++m)
#pragma unroll
        for (int n = 0; n < 8; ++n) acc[m][n] = zero4;

    // prologue: stage B(0), B(1); __syncthreads drains DMA + publishes bits
    STAGEB(0, 0);
    STAGEB(1, 1);
    __syncthreads();

    int cb = 0;
    for (int t = 0; t < NSTEP; ++t) {
        if (t > 0) {
            if (t < NSTEP - 1) asm volatile("s_waitcnt vmcnt(2)" ::: "memory");
            else               asm volatile("s_waitcnt vmcnt(0)" ::: "memory");
            __builtin_amdgcn_sched_barrier(0);
            __builtin_amdgcn_s_barrier();
            __builtin_amdgcn_sched_barrier(0);
        }
        if (t + 2 < NSTEP) {
            int nb2 = (cb >= 1) ? cb - 1 : cb + 2;   // (t+2)%3
            STAGEB(t + 2, nb2);
        }
        const char* bB = bufB[cb];

        bf16x8 af[4];
#pragma unroll
        for (int m = 0; m < 4; ++m) {
            int row = wm * 64 + m * 16 + lr;
            unsigned int bits = bitlds[row * 36 + t];
            af[m] = bits2bf(bits, lq * 8);
        }
#pragma unroll
        for (int n = 0; n < 8; ++n) {
            int col = wn * 128 + n * 16 + lr;
            bf16x8 bf = *(const bf16x8*)(bB + col * 64 + ((lq ^ (lr & 3)) << 4));
#pragma unroll
            for (int m = 0; m < 4; ++m)
                acc[m][n] = __builtin_amdgcn_mfma_f32_16x16x32_bf16(af[m], bf, acc[m][n], 0, 0, 0);
        }
        cb = (cb == 2) ? 0 : cb + 1;
    }
#undef STAGEB

    // C write (layout: col=lane&15, row=(lane>>4)*4+reg); nontemporal
    float* pbase = part + (size_t)kb * N_ROWS * D;
#pragma unroll
    for (int m = 0; m < 4; ++m)
#pragma unroll
        for (int n = 0; n < 8; ++n) {
            int orow = i0 + wm * 64 + m * 16 + lq * 4;
            int ocol = wn * 128 + n * 16 + lr;
            float* op = pbase + (size_t)orow * D + ocol;
#pragma unroll
            for (int vv = 0; vv < 4; ++vv)
                __builtin_nontemporal_store(acc[m][n][vv], op + (size_t)vv * D);
        }
}

// K5: split-K reduce + epilogue (divide, elu, proj, logmap0, sigmoid, expmap0)
__global__ void k_final3(const float* __restrict__ part, const float* __restrict__ rowsum,
                         float* __restrict__ out) {
    __shared__ float sb[4];
    int row = blockIdx.x, t = threadIdx.x;
    float raw = 0.f;
#pragma unroll
    for (int kbi = 0; kbi < NKB; ++kbi)
        raw += __builtin_nontemporal_load(&part[((size_t)kbi * N_ROWS + row) * D + t]);
    float rs = rowsum[row];
    float hp = raw / rs;
    float ey = 0.f;
    if (t >= 1) ey = (hp > 0.f) ? hp : expm1f(hp);
    float ss = breduce_sum256(ey * ey, sb);
    float x0 = sqrtf(1.f + ss);
    float th = fmaxf(x0, 1.f + 1e-7f);
    float al = acoshf(th);
    float yn = fmaxf(sqrtf(ss), 1e-15f);
    float u = (t >= 1) ? (al * ey / yn) : 0.f;
    float s = 1.f / (1.f + expf(-u));
    float s2 = (t >= 1) ? s * s : 0.f;
    float ssn = breduce_sum256(s2, sb);
    float xn = fmaxf(sqrtf(ssn), 1e-15f);
    float sh = sinhf(xn);
    float yf = (t >= 1) ? (sh * s / xn) : 0.f;
    float sy = breduce_sum256(yf * yf, sb);
    float res = (t == 0) ? sqrtf(1.f + sy) : yf;
    out[(size_t)row * D + t] = res;
}

extern "C" void kernel_launch(void* const* d_in, const int* in_sizes, int n_in,
                              void* d_out, int out_size, void* d_ws, size_t ws_size,
                              hipStream_t stream) {
    const float* x    = (const float*)d_in[0];
    const int*   adj  = (const int*)d_in[1];
    const float* Wg   = (const float*)d_in[3];
    const float* Wa   = (const float*)d_in[4];
    const float* aatt = (const float*)d_in[5];
    float* out = (float*)d_out;

    char* wsb = (char*)d_ws;
    unsigned short* M2Thi  = (unsigned short*)(wsb);              // 128 KB
    unsigned short* M2Tlo  = (unsigned short*)(wsb + 0x0020000);  // 128 KB
    float*          v      = (float*)(wsb + 0x0040000);           // 1 KB
    float*          wexp   = (float*)(wsb + 0x0048000);           // 32 KB
    float*          rowsum = (float*)(wsb + 0x0050000);           // 32 KB
    unsigned short* Awhi   = (unsigned short*)(wsb + 0x0100000);  // 4 MB
    unsigned short* Awlo   = (unsigned short*)(wsb + 0x0500000);  // 4 MB
    unsigned short* GT     = (unsigned short*)(wsb + 0x0900000);  // 4 MB
    float*          part   = (float*)(wsb + 0x1000000);           // 64 MB (NKB x 8 MB)
    unsigned long long* pack64 = (unsigned long long*)(wsb + 0x5000000); // 8 MB

    k_M2v<<<255, 256, 0, stream>>>(Wg, Wa, aatt, M2Thi, M2Tlo, v);
    k_logw<<<N_ROWS / 8, 256, 0, stream>>>(x, v, wexp, Awhi, Awlo);
    k_pack<<<N_ROWS / 8, 512, 0, stream>>>(adj, wexp, pack64, rowsum);
    k_hGT<<<N_ROWS / 64, 512, 0, stream>>>(M2Thi, M2Tlo, Awhi, Awlo, GT);
    k_attbits<<<32 * NKB, 512, 0, stream>>>((const unsigned int*)pack64, GT, part);
    k_final3<<<N_ROWS, 256, 0, stream>>>(part, rowsum, out);
}

// Round 17
// 178.592 us; speedup vs baseline: 1.2729x; 1.0278x over previous
//
#include <hip/hip_runtime.h>
#include <hip/hip_bf16.h>
#include <math.h>

typedef __attribute__((ext_vector_type(4))) float f32x4;
typedef __attribute__((ext_vector_type(8))) short bf16x8;

#define N_ROWS 8192
#define D 256
#define MSHIFT 16.0f
#define NKB 8
#define KRANGE (N_ROWS / NKB)     // 1024
#define NSTEP (KRANGE / 32)       // 32 (BK=32)

__device__ __forceinline__ unsigned short f2bf(float f) {
    unsigned int u = __float_as_uint(f);
    unsigned int r = u + 0x7FFFu + ((u >> 16) & 1u);
    return (unsigned short)(r >> 16);
}
__device__ __forceinline__ float bf2f(unsigned short h) {
    return __uint_as_float(((unsigned int)h) << 16);
}

__device__ __forceinline__ float breduce_sum256(float v, float* sb) {
#pragma unroll
    for (int off = 32; off; off >>= 1) v += __shfl_down(v, off);
    int wid = threadIdx.x >> 6;
    __syncthreads();
    if ((threadIdx.x & 63) == 0) sb[wid] = v;
    __syncthreads();
    return sb[0] + sb[1] + sb[2] + sb[3];
}

__device__ __forceinline__ void dma16(const void* g, void* l) {
    __builtin_amdgcn_global_load_lds(
        (const __attribute__((address_space(1))) unsigned int*)g,
        (__attribute__((address_space(3))) unsigned int*)l, 16, 0, 0);
}

// expand 8 adjacency bits (starting at bit sh of w32) to bf16 0/1
__device__ __forceinline__ bf16x8 bits2bf(unsigned int w32, int sh) {
    unsigned int m = w32 >> sh;
    bf16x8 r;
#pragma unroll
    for (int j = 0; j < 8; ++j)
        r[j] = (m & (1u << j)) ? (short)0x3F80 : (short)0;
    return r;
}

// K0: block-contiguous pack. Whole block streams ONE row at a time (8 KB
// contiguous per step; 1024 blocks = 1024 fill-like streams -> no HBM row
// thrash). Wave w covers k-slice [1024w, 1024w+1024) via 4 int4 loads.
// Bits assembled per-lane nibble -> shift -> 4-step shfl_xor OR-butterfly
// (canonical bit order, identical to ballot layout). Exact f32 rowsum folded.
__global__ void __launch_bounds__(512)
k_pack(const int* __restrict__ adj, const float* __restrict__ wexp,
       unsigned long long* __restrict__ pack64, float* __restrict__ rowsum) {
    __shared__ float wlds[N_ROWS];
    __shared__ float rsred[8][8];
    const int tid = threadIdx.x;
    const int w = tid >> 6, l = tid & 63;
    const int row0 = blockIdx.x * 8;
    // stage wexp (32 KB) once per block, coalesced float4
#pragma unroll
    for (int i = 0; i < 4; ++i) {
        float4 v4 = *(const float4*)(wexp + (i * 512 + tid) * 4);
        *(float4*)(&wlds[(i * 512 + tid) * 4]) = v4;
    }
    __syncthreads();

    const size_t koff = (size_t)w * 1024 + l * 4;
    const int* base = adj + (size_t)row0 * N_ROWS + koff;
    int4 abuf[2][4];
#pragma unroll
    for (int i = 0; i < 4; ++i)
        abuf[0][i] = *(const int4*)(base + i * 256);

    for (int r = 0; r < 8; ++r) {
        if (r + 1 < 8) {
#pragma unroll
            for (int i = 0; i < 4; ++i)
                abuf[(r + 1) & 1][i] = *(const int4*)(base + (size_t)(r + 1) * N_ROWS + i * 256);
        }
        __builtin_amdgcn_sched_barrier(0);   // prefetch issued before this row's VALU
        const int4* A = abuf[r & 1];
        float rs = 0.f;
#pragma unroll
        for (int i = 0; i < 4; ++i) {
            int4 a = A[i];
            float4 wv = *(const float4*)(&wlds[w * 1024 + i * 256 + l * 4]);
            unsigned int nb = (a.x ? 1u : 0u) | (a.y ? 2u : 0u) |
                              (a.z ? 4u : 0u) | (a.w ? 8u : 0u);
            unsigned long long v = (unsigned long long)nb << (4 * (l & 15));
            rs += (a.x ? wv.x : 0.f) + (a.y ? wv.y : 0.f) +
                  (a.z ? wv.z : 0.f) + (a.w ? wv.w : 0.f);
            v |= __shfl_xor(v, 1);
            v |= __shfl_xor(v, 2);
            v |= __shfl_xor(v, 4);
            v |= __shfl_xor(v, 8);
            if ((l & 15) == 0)
                pack64[(size_t)(row0 + r) * 128 + w * 16 + i * 4 + (l >> 4)] = v;
        }
#pragma unroll
        for (int off = 32; off; off >>= 1) rs += __shfl_xor(rs, off);
        if (l == 0) rsred[r][w] = rs;
    }
    __syncthreads();
    if (tid < 8) {
        float s = 0.f;
#pragma unroll
        for (int j = 0; j < 8; ++j) s += rsred[tid][j];
        rowsum[row0 + tid] = s;
    }
}

// K1: M2 row k (f32) -> M2T hi/lo bf16 split [j][k]; v[k] = sum_j M2[k][j]*a2[j]
__global__ void k_M2v(const float* __restrict__ Wg, const float* __restrict__ Wa,
                      const float* __restrict__ aatt,
                      unsigned short* __restrict__ M2Thi, unsigned short* __restrict__ M2Tlo,
                      float* __restrict__ v) {
    __shared__ float sb[4];
    int k = blockIdx.x, t = threadIdx.x;
    float acc = 0.f;
#pragma unroll 8
    for (int m = 0; m < 255; ++m)
        acc += Wg[k * 255 + m] * Wa[(m + 1) * 256 + t];
    unsigned short hi = f2bf(acc);
    unsigned short lo = f2bf(acc - bf2f(hi));
    M2Thi[t * 256 + k] = hi;
    M2Tlo[t * 256 + k] = lo;
    if (k == 0) { M2Thi[t * 256 + 255] = 0; M2Tlo[t * 256 + 255] = 0; }
    float s = breduce_sum256(acc * aatt[256 + t], sb);
    if (t == 0) v[k] = s;
}

// K2: per-row logmap0 + c = logx.v -> wexp (f32); write w-scaled logx hi/lo bf16 (k-shifted)
__global__ void k_logw(const float* __restrict__ x, const float* __restrict__ v,
                       float* __restrict__ wexp,
                       unsigned short* __restrict__ Awhi, unsigned short* __restrict__ Awlo) {
    __shared__ float sb[4];
    int i0 = blockIdx.x * 8, t = threadIdx.x;
    float vv = (t >= 1) ? v[t - 1] : 0.f;
#pragma unroll
    for (int r = 0; r < 8; ++r) {
        float xv = x[(size_t)(i0 + r) * D + t];
        float yv = (t >= 1) ? xv : 0.f;
        float ss = breduce_sum256(yv * yv, sb);
        float x0 = x[(size_t)(i0 + r) * D];
        float coef = acoshf(fmaxf(x0, 1.f + 1e-7f)) / fmaxf(sqrtf(ss), 1e-15f);
        float lg = coef * yv;                 // logx[i][t]
        float c = breduce_sum256(lg * vv, sb);
        float w = expf(c - MSHIFT);
        if (t == r) wexp[i0 + r] = w;
        float aw = w * lg;
        unsigned short hi = f2bf(aw);
        unsigned short lo = f2bf(aw - bf2f(hi));
        int kd = (t == 0) ? 255 : (t - 1);    // Aw[i][k] = w*logx[i][k+1], pad k=255 -> 0
        Awhi[(size_t)(i0 + r) * 256 + kd] = hi;
        Awlo[(size_t)(i0 + r) * 256 + kd] = lo;
    }
}

// K3: GT[c][i] = sum_k M2T[c][k] * Aw[i][k]  (3-term hi/lo MFMA). 512 thr, 64 i-cols/block.
__global__ void __launch_bounds__(512)
k_hGT(const unsigned short* __restrict__ M2Thi, const unsigned short* __restrict__ M2Tlo,
      const unsigned short* __restrict__ Awhi, const unsigned short* __restrict__ Awlo,
      unsigned short* __restrict__ GT) {
    __shared__ __align__(16) char ahi[32768], alo[32768], bhi[8192], blo[8192];
    const int tid = threadIdx.x;
    const int w = tid >> 6, l = tid & 63;
    const int lr = l & 15, lq = l >> 4;
    const int i0 = blockIdx.x * 64;
    const int gs = (l & 7) ^ (l >> 3);

    const unsigned short* srcAhi[4];
    const unsigned short* srcAlo[4];
#pragma unroll
    for (int i = 0; i < 4; ++i) {
        int rowA = (w * 4 + i) * 8 + (l >> 3);
        srcAhi[i] = M2Thi + rowA * 256 + gs * 8;
        srcAlo[i] = M2Tlo + rowA * 256 + gs * 8;
    }
    int rowB = w * 8 + (l >> 3);
    const unsigned short* srcBhi = Awhi + (size_t)(i0 + rowB) * 256 + gs * 8;
    const unsigned short* srcBlo = Awlo + (size_t)(i0 + rowB) * 256 + gs * 8;

    f32x4 zero4 = {0.f, 0.f, 0.f, 0.f};
    f32x4 acc[2][4];
#pragma unroll
    for (int m = 0; m < 2; ++m)
#pragma unroll
        for (int n = 0; n < 4; ++n) acc[m][n] = zero4;

    for (int t = 0; t < 4; ++t) {
        if (t) __syncthreads();
#pragma unroll
        for (int i = 0; i < 4; ++i) {
            dma16(srcAhi[i] + t * 64, ahi + (w * 4 + i) * 1024);
            dma16(srcAlo[i] + t * 64, alo + (w * 4 + i) * 1024);
        }
        dma16(srcBhi + t * 64, bhi + w * 1024);
        dma16(srcBlo + t * 64, blo + w * 1024);
        asm volatile("s_waitcnt vmcnt(0)" ::: "memory");
        __syncthreads();
#pragma unroll
        for (int ks = 0; ks < 2; ++ks) {
            const int g = ((ks * 4 + lq) ^ (lr & 7)) * 16;
            bf16x8 afh[2], afl[2];
#pragma unroll
            for (int m = 0; m < 2; ++m) {
                int row = w * 32 + m * 16 + lr;
                afh[m] = *(const bf16x8*)(ahi + row * 128 + g);
                afl[m] = *(const bf16x8*)(alo + row * 128 + g);
            }
#pragma unroll
            for (int n = 0; n < 4; ++n) {
                int rb = n * 16 + lr;
                bf16x8 bfh = *(const bf16x8*)(bhi + rb * 128 + g);
                bf16x8 bfl = *(const bf16x8*)(blo + rb * 128 + g);
#pragma unroll
                for (int m = 0; m < 2; ++m) {
                    acc[m][n] = __builtin_amdgcn_mfma_f32_16x16x32_bf16(afh[m], bfh, acc[m][n], 0, 0, 0);
                    acc[m][n] = __builtin_amdgcn_mfma_f32_16x16x32_bf16(afh[m], bfl, acc[m][n], 0, 0, 0);
                    acc[m][n] = __builtin_amdgcn_mfma_f32_16x16x32_bf16(afl[m], bfh, acc[m][n], 0, 0, 0);
                }
            }
        }
    }
#pragma unroll
    for (int m = 0; m < 2; ++m)
#pragma unroll
        for (int n = 0; n < 4; ++n)
#pragma unroll
            for (int vv = 0; vv < 4; ++vv) {
                int c = w * 32 + m * 16 + lq * 4 + vv;
                GT[(size_t)c * N_ROWS + i0 + n * 16 + lr] = f2bf(acc[m][n][vv]);
            }
}

// K4: masked GEMM from bit-mask. BM=256, BN=256, BK=32, NKB=8. 512 thr (8 waves, 4m x 2n).
// A: block's whole 256-row x 1024-k bit slice (32 KB, pad-36) staged ONCE.
// B: 16 KB/step from XCD-pinned L2 GT slice; triple-buffer, stage(t+2) after
// barrier, counted vmcnt(2). No per-step A traffic.
__global__ void __launch_bounds__(512)
k_attbits(const unsigned int* __restrict__ pack32, const unsigned short* __restrict__ GT,
          float* __restrict__ part) {
    __shared__ __align__(16) unsigned int bitlds[256 * 36];  // cols 0..31 used
    __shared__ __align__(16) char bufB[3][16384];            // 256 cols x 32 bf16
    const int tid = threadIdx.x;
    const int kb = blockIdx.x & 7;         // XCD-pinned GT k-slice
    const int rb = blockIdx.x >> 3;        // 0..31
    const int i0 = rb * 256;
    const int kbeg = kb * KRANGE;
    const int w = tid >> 6, l = tid & 63;
    const int lr = l & 15, lq = l >> 4;
    const int wm = w >> 1, wn = w & 1;     // 4 row-groups x 2 col-groups

    // ---- bits prologue: 32 KB coalesced (8 lanes x 16B per row)
    {
        const int rloc = tid >> 3, gb = tid & 7;
#pragma unroll
        for (int p = 0; p < 4; ++p) {
            uint4 vb = *(const uint4*)(pack32 + (size_t)(i0 + p * 64 + rloc) * 256 + kb * 32 + gb * 4);
            *(uint4*)(bitlds + (p * 64 + rloc) * 36 + gb * 4) = vb;
        }
    }

    // ---- B dma sources (pre-swizzled granule; 2 insts/wave)
    const int col4 = l >> 2, gB = ((l & 3) ^ (col4 & 3)) * 8;
    const unsigned short* srcB[2];
#pragma unroll
    for (int i = 0; i < 2; ++i) {
        int b = w * 2 + i;
        srcB[i] = GT + (size_t)(b * 16 + col4) * N_ROWS + kbeg + gB;
    }
#define STAGEB(T_, BI_) do {                                           \
        _Pragma("unroll")                                              \
        for (int i_ = 0; i_ < 2; ++i_)                                 \
            dma16(srcB[i_] + (T_) * 32, bufB[BI_] + (w * 2 + i_) * 1024); \
    } while (0)

    f32x4 zero4 = {0.f, 0.f, 0.f, 0.f};
    f32x4 acc[4][8];
#pragma unroll
    for (int m = 0; m < 4; ++m)
#pragma unroll
        for (int n = 0; n < 8; ++n) acc[m][n] = zero4;

    // prologue: stage B(0), B(1); __syncthreads drains DMA + publishes bits
    STAGEB(0, 0);
    STAGEB(1, 1);
    __syncthreads();

    int cb = 0;
    for (int t = 0; t < NSTEP; ++t) {
        if (t > 0) {
            if (t < NSTEP - 1) asm volatile("s_waitcnt vmcnt(2)" ::: "memory");
            else               asm volatile("s_waitcnt vmcnt(0)" ::: "memory");
            __builtin_amdgcn_sched_barrier(0);
            __builtin_amdgcn_s_barrier();
            __builtin_amdgcn_sched_barrier(0);
        }
        if (t + 2 < NSTEP) {
            int nb2 = (cb >= 1) ? cb - 1 : cb + 2;   // (t+2)%3
            STAGEB(t + 2, nb2);
        }
        const char* bB = bufB[cb];

        bf16x8 af[4];
#pragma unroll
        for (int m = 0; m < 4; ++m) {
            int row = wm * 64 + m * 16 + lr;
            unsigned int bits = bitlds[row * 36 + t];
            af[m] = bits2bf(bits, lq * 8);
        }
#pragma unroll
        for (int n = 0; n < 8; ++n) {
            int col = wn * 128 + n * 16 + lr;
            bf16x8 bf = *(const bf16x8*)(bB + col * 64 + ((lq ^ (lr & 3)) << 4));
#pragma unroll
            for (int m = 0; m < 4; ++m)
                acc[m][n] = __builtin_amdgcn_mfma_f32_16x16x32_bf16(af[m], bf, acc[m][n], 0, 0, 0);
        }
        cb = (cb == 2) ? 0 : cb + 1;
    }
#undef STAGEB

    // C write (layout: col=lane&15, row=(lane>>4)*4+reg); nontemporal
    float* pbase = part + (size_t)kb * N_ROWS * D;
#pragma unroll
    for (int m = 0; m < 4; ++m)
#pragma unroll
        for (int n = 0; n < 8; ++n) {
            int orow = i0 + wm * 64 + m * 16 + lq * 4;
            int ocol = wn * 128 + n * 16 + lr;
            float* op = pbase + (size_t)orow * D + ocol;
#pragma unroll
            for (int vv = 0; vv < 4; ++vv)
                __builtin_nontemporal_store(acc[m][n][vv], op + (size_t)vv * D);
        }
}

// K5: split-K reduce + epilogue (divide, elu, proj, logmap0, sigmoid, expmap0)
__global__ void k_final3(const float* __restrict__ part, const float* __restrict__ rowsum,
                         float* __restrict__ out) {
    __shared__ float sb[4];
    int row = blockIdx.x, t = threadIdx.x;
    float raw = 0.f;
#pragma unroll
    for (int kbi = 0; kbi < NKB; ++kbi)
        raw += __builtin_nontemporal_load(&part[((size_t)kbi * N_ROWS + row) * D + t]);
    float rs = rowsum[row];
    float hp = raw / rs;
    float ey = 0.f;
    if (t >= 1) ey = (hp > 0.f) ? hp : expm1f(hp);
    float ss = breduce_sum256(ey * ey, sb);
    float x0 = sqrtf(1.f + ss);
    float th = fmaxf(x0, 1.f + 1e-7f);
    float al = acoshf(th);
    float yn = fmaxf(sqrtf(ss), 1e-15f);
    float u = (t >= 1) ? (al * ey / yn) : 0.f;
    float s = 1.f / (1.f + expf(-u));
    float s2 = (t >= 1) ? s * s : 0.f;
    float ssn = breduce_sum256(s2, sb);
    float xn = fmaxf(sqrtf(ssn), 1e-15f);
    float sh = sinhf(xn);
    float yf = (t >= 1) ? (sh * s / xn) : 0.f;
    float sy = breduce_sum256(yf * yf, sb);
    float res = (t == 0) ? sqrtf(1.f + sy) : yf;
    out[(size_t)row * D + t] = res;
}

extern "C" void kernel_launch(void* const* d_in, const int* in_sizes, int n_in,
                              void* d_out, int out_size, void* d_ws, size_t ws_size,
                              hipStream_t stream) {
    const float* x    = (const float*)d_in[0];
    const int*   adj  = (const int*)d_in[1];
    const float* Wg   = (const float*)d_in[3];
    const float* Wa   = (const float*)d_in[4];
    const float* aatt = (const float*)d_in[5];
    float* out = (float*)d_out;

    char* wsb = (char*)d_ws;
    unsigned short* M2Thi  = (unsigned short*)(wsb);              // 128 KB
    unsigned short* M2Tlo  = (unsigned short*)(wsb + 0x0020000);  // 128 KB
    float*          v      = (float*)(wsb + 0x0040000);           // 1 KB
    float*          wexp   = (float*)(wsb + 0x0048000);           // 32 KB
    float*          rowsum = (float*)(wsb + 0x0050000);           // 32 KB
    unsigned short* Awhi   = (unsigned short*)(wsb + 0x0100000);  // 4 MB
    unsigned short* Awlo   = (unsigned short*)(wsb + 0x0500000);  // 4 MB
    unsigned short* GT     = (unsigned short*)(wsb + 0x0900000);  // 4 MB
    float*          part   = (float*)(wsb + 0x1000000);           // 64 MB (NKB x 8 MB)
    unsigned long long* pack64 = (unsigned long long*)(wsb + 0x5000000); // 8 MB

    k_M2v<<<255, 256, 0, stream>>>(Wg, Wa, aatt, M2Thi, M2Tlo, v);
    k_logw<<<N_ROWS / 8, 256, 0, stream>>>(x, v, wexp, Awhi, Awlo);
    k_pack<<<N_ROWS / 8, 512, 0, stream>>>(adj, wexp, pack64, rowsum);
    k_hGT<<<N_ROWS / 64, 512, 0, stream>>>(M2Thi, M2Tlo, Awhi, Awlo, GT);
    k_attbits<<<32 * NKB, 512, 0, stream>>>((const unsigned int*)pack64, GT, part);
    k_final3<<<N_ROWS, 256, 0, stream>>>(part, rowsum, out);
}

// Round 18
// 171.419 us; speedup vs baseline: 1.3262x; 1.0418x over previous
//
#include <hip/hip_runtime.h>
#include <hip/hip_bf16.h>
#include <math.h>

typedef __attribute__((ext_vector_type(4))) float f32x4;
typedef __attribute__((ext_vector_type(8))) short bf16x8;

#define N_ROWS 8192
#define D 256
#define MSHIFT 16.0f
#define NKB 8
#define KRANGE (N_ROWS / NKB)     // 1024
#define NSTEP (KRANGE / 32)       // 32 (BK=32)

__device__ __forceinline__ unsigned short f2bf(float f) {
    unsigned int u = __float_as_uint(f);
    unsigned int r = u + 0x7FFFu + ((u >> 16) & 1u);
    return (unsigned short)(r >> 16);
}
__device__ __forceinline__ float bf2f(unsigned short h) {
    return __uint_as_float(((unsigned int)h) << 16);
}

__device__ __forceinline__ float breduce_sum256(float v, float* sb) {
#pragma unroll
    for (int off = 32; off; off >>= 1) v += __shfl_down(v, off);
    int wid = threadIdx.x >> 6;
    __syncthreads();
    if ((threadIdx.x & 63) == 0) sb[wid] = v;
    __syncthreads();
    return sb[0] + sb[1] + sb[2] + sb[3];
}

__device__ __forceinline__ void dma16(const void* g, void* l) {
    __builtin_amdgcn_global_load_lds(
        (const __attribute__((address_space(1))) unsigned int*)g,
        (__attribute__((address_space(3))) unsigned int*)l, 16, 0, 0);
}

__device__ __forceinline__ bf16x8 adj2bf(int4 a, int4 b) {
    bf16x8 r;
    r[0] = a.x ? (short)0x3F80 : (short)0;
    r[1] = a.y ? (short)0x3F80 : (short)0;
    r[2] = a.z ? (short)0x3F80 : (short)0;
    r[3] = a.w ? (short)0x3F80 : (short)0;
    r[4] = b.x ? (short)0x3F80 : (short)0;
    r[5] = b.y ? (short)0x3F80 : (short)0;
    r[6] = b.z ? (short)0x3F80 : (short)0;
    r[7] = b.w ? (short)0x3F80 : (short)0;
    return r;
}

// K1: M2 row k (f32) -> M2T hi/lo bf16 split [j][k]; v[k] = sum_j M2[k][j]*a2[j]
__global__ void k_M2v(const float* __restrict__ Wg, const float* __restrict__ Wa,
                      const float* __restrict__ aatt,
                      unsigned short* __restrict__ M2Thi, unsigned short* __restrict__ M2Tlo,
                      float* __restrict__ v) {
    __shared__ float sb[4];
    int k = blockIdx.x, t = threadIdx.x;
    float acc = 0.f;
#pragma unroll 8
    for (int m = 0; m < 255; ++m)
        acc += Wg[k * 255 + m] * Wa[(m + 1) * 256 + t];
    unsigned short hi = f2bf(acc);
    unsigned short lo = f2bf(acc - bf2f(hi));
    M2Thi[t * 256 + k] = hi;
    M2Tlo[t * 256 + k] = lo;
    if (k == 0) { M2Thi[t * 256 + 255] = 0; M2Tlo[t * 256 + 255] = 0; }
    float s = breduce_sum256(acc * aatt[256 + t], sb);
    if (t == 0) v[k] = s;
}

// K2: per-row logmap0 + c = logx.v + wexp; write wbf (bf16) and w-scaled logx hi/lo bf16
__global__ void k_logw(const float* __restrict__ x, const float* __restrict__ v,
                       unsigned short* __restrict__ wbf,
                       unsigned short* __restrict__ Awhi, unsigned short* __restrict__ Awlo) {
    __shared__ float sb[4];
    int i0 = blockIdx.x * 8, t = threadIdx.x;
    float vv = (t >= 1) ? v[t - 1] : 0.f;
#pragma unroll
    for (int r = 0; r < 8; ++r) {
        float xv = x[(size_t)(i0 + r) * D + t];
        float yv = (t >= 1) ? xv : 0.f;
        float ss = breduce_sum256(yv * yv, sb);
        float x0 = x[(size_t)(i0 + r) * D];
        float coef = acoshf(fmaxf(x0, 1.f + 1e-7f)) / fmaxf(sqrtf(ss), 1e-15f);
        float lg = coef * yv;                 // logx[i][t]
        float c = breduce_sum256(lg * vv, sb);
        float w = expf(c - MSHIFT);
        if (t == r) wbf[i0 + r] = f2bf(w);
        float aw = w * lg;
        unsigned short hi = f2bf(aw);
        unsigned short lo = f2bf(aw - bf2f(hi));
        int kd = (t == 0) ? 255 : (t - 1);    // Aw[i][k] = w*logx[i][k+1], pad k=255 -> 0
        Awhi[(size_t)(i0 + r) * 256 + kd] = hi;
        Awlo[(size_t)(i0 + r) * 256 + kd] = lo;
    }
}

// K3: GT[c][i] = sum_k M2T[c][k] * Aw[i][k]  (3-term hi/lo MFMA). 512 thr, 64 i-cols/block.
__global__ void __launch_bounds__(512)
k_hGT(const unsigned short* __restrict__ M2Thi, const unsigned short* __restrict__ M2Tlo,
      const unsigned short* __restrict__ Awhi, const unsigned short* __restrict__ Awlo,
      unsigned short* __restrict__ GT) {
    __shared__ __align__(16) char ahi[32768], alo[32768], bhi[8192], blo[8192];
    const int tid = threadIdx.x;
    const int w = tid >> 6, l = tid & 63;
    const int lr = l & 15, lq = l >> 4;
    const int i0 = blockIdx.x * 64;
    const int gs = (l & 7) ^ (l >> 3);

    const unsigned short* srcAhi[4];
    const unsigned short* srcAlo[4];
#pragma unroll
    for (int i = 0; i < 4; ++i) {
        int rowA = (w * 4 + i) * 8 + (l >> 3);
        srcAhi[i] = M2Thi + rowA * 256 + gs * 8;
        srcAlo[i] = M2Tlo + rowA * 256 + gs * 8;
    }
    int rowB = w * 8 + (l >> 3);
    const unsigned short* srcBhi = Awhi + (size_t)(i0 + rowB) * 256 + gs * 8;
    const unsigned short* srcBlo = Awlo + (size_t)(i0 + rowB) * 256 + gs * 8;

    f32x4 zero4 = {0.f, 0.f, 0.f, 0.f};
    f32x4 acc[2][4];
#pragma unroll
    for (int m = 0; m < 2; ++m)
#pragma unroll
        for (int n = 0; n < 4; ++n) acc[m][n] = zero4;

    for (int t = 0; t < 4; ++t) {
        if (t) __syncthreads();
#pragma unroll
        for (int i = 0; i < 4; ++i) {
            dma16(srcAhi[i] + t * 64, ahi + (w * 4 + i) * 1024);
            dma16(srcAlo[i] + t * 64, alo + (w * 4 + i) * 1024);
        }
        dma16(srcBhi + t * 64, bhi + w * 1024);
        dma16(srcBlo + t * 64, blo + w * 1024);
        asm volatile("s_waitcnt vmcnt(0)" ::: "memory");
        __syncthreads();
#pragma unroll
        for (int ks = 0; ks < 2; ++ks) {
            const int g = ((ks * 4 + lq) ^ (lr & 7)) * 16;
            bf16x8 afh[2], afl[2];
#pragma unroll
            for (int m = 0; m < 2; ++m) {
                int row = w * 32 + m * 16 + lr;
                afh[m] = *(const bf16x8*)(ahi + row * 128 + g);
                afl[m] = *(const bf16x8*)(alo + row * 128 + g);
            }
#pragma unroll
            for (int n = 0; n < 4; ++n) {
                int rb = n * 16 + lr;
                bf16x8 bfh = *(const bf16x8*)(bhi + rb * 128 + g);
                bf16x8 bfl = *(const bf16x8*)(blo + rb * 128 + g);
#pragma unroll
                for (int m = 0; m < 2; ++m) {
                    acc[m][n] = __builtin_amdgcn_mfma_f32_16x16x32_bf16(afh[m], bfh, acc[m][n], 0, 0, 0);
                    acc[m][n] = __builtin_amdgcn_mfma_f32_16x16x32_bf16(afh[m], bfl, acc[m][n], 0, 0, 0);
                    acc[m][n] = __builtin_amdgcn_mfma_f32_16x16x32_bf16(afl[m], bfh, acc[m][n], 0, 0, 0);
                }
            }
        }
    }
#pragma unroll
    for (int m = 0; m < 2; ++m)
#pragma unroll
        for (int n = 0; n < 4; ++n)
#pragma unroll
            for (int vv = 0; vv < 4; ++vv) {
                int c = w * 32 + m * 16 + lq * 4 + vv;
                GT[(size_t)c * N_ROWS + i0 + n * 16 + lr] = f2bf(acc[m][n][vv]);
            }
}

// K4: fused masked GEMM (R12 structure + attbits schedule). BM=256, BN=256, BK=32,
// NKB=8, 512 thr (8 waves, 4m x 2n). Triple-buffered, 2-AHEAD pipeline:
// prologue stages steps 0,1 (+wlds), syncthreads; per-iter:
// wait vmcnt(6|0) -> s_barrier -> STAGE(t+2) -> compute(t). 96 KB in flight.
// Rowsum folded as wexp-bf16 B-column MFMA. part stored as bf16 (halved traffic).
__global__ void __launch_bounds__(512)
k_attadj(const int* __restrict__ adj, const unsigned short* __restrict__ GT,
         const unsigned short* __restrict__ wbf, unsigned short* __restrict__ part,
         float* __restrict__ rspart) {
    __shared__ __align__(16) char bufA[3 * 32768];   // 256 rows x 32 ints (128 B rows)
    __shared__ __align__(16) char bufB[3 * 16384];   // 256 cols x 32 bf16 (64 B rows)
    __shared__ __align__(16) char wlds[2048];        // KRANGE bf16 weights
    const int tid = threadIdx.x;
    const int kb = blockIdx.x & 7;         // XCD-pinned GT k-slice
    const int rb = blockIdx.x >> 3;        // 0..31
    const int i0 = rb * 256;
    const int kbeg = kb * KRANGE;
    const int w = tid >> 6, l = tid & 63;
    const int lr = l & 15, lq = l >> 4;
    const int wm = w >> 1, wn = w & 1;     // 4 row-groups x 2 col-groups

    // A dma: 32 insts (4/wave): inst a covers rows a*8..+7; lane: row8=l>>3,
    // granule g=l&7 (16B=4 ints); LDS[row][g] = global[row][g ^ (row&7)]
    const int row8 = l >> 3, gA = (l & 7) ^ row8;
    const int* srcA[4];
#pragma unroll
    for (int i = 0; i < 4; ++i) {
        int a = w * 4 + i;
        srcA[i] = adj + (size_t)(i0 + a * 8 + row8) * N_ROWS + kbeg + gA * 4;
    }
    // B dma: 16 insts (2/wave): inst b covers cols b*16..+15; lane: col4=l>>2,
    // g2 (16B=8 bf16); LDS[col][g2] = global[col][g2 ^ (col&3)]
    const int col4 = l >> 2, gB = ((l & 3) ^ (col4 & 3)) * 8;
    const unsigned short* srcB[2];
#pragma unroll
    for (int i = 0; i < 2; ++i) {
        int b = w * 2 + i;
        srcB[i] = GT + (size_t)(b * 16 + col4) * N_ROWS + kbeg + gB;
    }

#define STAGE(T_, BI_) do {                                                \
        _Pragma("unroll")                                                  \
        for (int i_ = 0; i_ < 4; ++i_)                                     \
            dma16(srcA[i_] + (T_) * 32, bufA + (BI_) * 32768 + (w * 4 + i_) * 1024); \
        _Pragma("unroll")                                                  \
        for (int i_ = 0; i_ < 2; ++i_)                                     \
            dma16(srcB[i_] + (T_) * 32, bufB + (BI_) * 16384 + (w * 2 + i_) * 1024); \
    } while (0)

    f32x4 zero4 = {0.f, 0.f, 0.f, 0.f};
    f32x4 acc[4][8], acc_rs[4];
#pragma unroll
    for (int m = 0; m < 4; ++m) {
        acc_rs[m] = zero4;
#pragma unroll
        for (int n = 0; n < 8; ++n) acc[m][n] = zero4;
    }

    // prologue: stage steps 0,1 + weight tile; syncthreads drains + publishes
    STAGE(0, 0);
    STAGE(1, 1);
    if (w < 2) dma16(wbf + kbeg + w * 512 + l * 8, wlds + w * 1024);
    __syncthreads();

    int cb = 0;
    for (int t = 0; t < NSTEP; ++t) {
        if (t > 0) {
            if (t < NSTEP - 1) asm volatile("s_waitcnt vmcnt(6)" ::: "memory");
            else               asm volatile("s_waitcnt vmcnt(0)" ::: "memory");
            __builtin_amdgcn_sched_barrier(0);
            __builtin_amdgcn_s_barrier();
            __builtin_amdgcn_sched_barrier(0);
        }
        if (t + 2 < NSTEP) {
            int nb2 = (cb >= 1) ? cb - 1 : cb + 2;   // (t+2)%3
            STAGE(t + 2, nb2);
        }
        const char* bA = bufA + cb * 32768;
        const char* bB = bufB + cb * 16384;

        bf16x8 wf = {0, 0, 0, 0, 0, 0, 0, 0};
        if (lr == 0) wf = *(const bf16x8*)(wlds + t * 64 + lq * 16);

        bf16x8 af[4];
#pragma unroll
        for (int m = 0; m < 4; ++m) {
            int row = wm * 64 + m * 16 + lr;
            int4 u  = *(const int4*)(bA + row * 128 + (((2 * lq) ^ (lr & 7)) << 4));
            int4 v2 = *(const int4*)(bA + row * 128 + (((2 * lq + 1) ^ (lr & 7)) << 4));
            af[m] = adj2bf(u, v2);
            acc_rs[m] = __builtin_amdgcn_mfma_f32_16x16x32_bf16(af[m], wf, acc_rs[m], 0, 0, 0);
        }
#pragma unroll
        for (int n = 0; n < 8; ++n) {
            int col = wn * 128 + n * 16 + lr;
            bf16x8 bf = *(const bf16x8*)(bB + col * 64 + ((lq ^ (lr & 3)) << 4));
#pragma unroll
            for (int m = 0; m < 4; ++m)
                acc[m][n] = __builtin_amdgcn_mfma_f32_16x16x32_bf16(af[m], bf, acc[m][n], 0, 0, 0);
        }
        cb = (cb == 2) ? 0 : cb + 1;
    }
#undef STAGE

    // rowsum (col 0 of acc_rs; wn duplicates -> wn==0 writes)
    if (wn == 0 && lr == 0) {
#pragma unroll
        for (int m = 0; m < 4; ++m)
#pragma unroll
            for (int vv = 0; vv < 4; ++vv)
                rspart[(size_t)kb * N_ROWS + i0 + wm * 64 + m * 16 + lq * 4 + vv] = acc_rs[m][vv];
    }

    // C write bf16 (layout: col=lane&15, row=(lane>>4)*4+reg); nontemporal
    unsigned short* pbase = part + (size_t)kb * N_ROWS * D;
#pragma unroll
    for (int m = 0; m < 4; ++m)
#pragma unroll
        for (int n = 0; n < 8; ++n) {
            int orow = i0 + wm * 64 + m * 16 + lq * 4;
            int ocol = wn * 128 + n * 16 + lr;
            unsigned short* op = pbase + (size_t)orow * D + ocol;
#pragma unroll
            for (int vv = 0; vv < 4; ++vv)
                __builtin_nontemporal_store(f2bf(acc[m][n][vv]), op + (size_t)vv * D);
        }
}

// K5: split-K reduce (bf16 part) + epilogue (divide, elu, proj, logmap0, sigmoid, expmap0)
__global__ void k_final3(const unsigned short* __restrict__ part, const float* __restrict__ rspart,
                         float* __restrict__ out) {
    __shared__ float sb[4];
    int row = blockIdx.x, t = threadIdx.x;
    float raw = 0.f, rs = 0.f;
#pragma unroll
    for (int kbi = 0; kbi < NKB; ++kbi) {
        raw += bf2f(__builtin_nontemporal_load(&part[((size_t)kbi * N_ROWS + row) * D + t]));
        rs += rspart[(size_t)kbi * N_ROWS + row];
    }
    float hp = raw / rs;
    float ey = 0.f;
    if (t >= 1) ey = (hp > 0.f) ? hp : expm1f(hp);
    float ss = breduce_sum256(ey * ey, sb);
    float x0 = sqrtf(1.f + ss);
    float th = fmaxf(x0, 1.f + 1e-7f);
    float al = acoshf(th);
    float yn = fmaxf(sqrtf(ss), 1e-15f);
    float u = (t >= 1) ? (al * ey / yn) : 0.f;
    float s = 1.f / (1.f + expf(-u));
    float s2 = (t >= 1) ? s * s : 0.f;
    float ssn = breduce_sum256(s2, sb);
    float xn = fmaxf(sqrtf(ssn), 1e-15f);
    float sh = sinhf(xn);
    float yf = (t >= 1) ? (sh * s / xn) : 0.f;
    float sy = breduce_sum256(yf * yf, sb);
    float res = (t == 0) ? sqrtf(1.f + sy) : yf;
    out[(size_t)row * D + t] = res;
}

extern "C" void kernel_launch(void* const* d_in, const int* in_sizes, int n_in,
                              void* d_out, int out_size, void* d_ws, size_t ws_size,
                              hipStream_t stream) {
    const float* x    = (const float*)d_in[0];
    const int*   adj  = (const int*)d_in[1];
    const float* Wg   = (const float*)d_in[3];
    const float* Wa   = (const float*)d_in[4];
    const float* aatt = (const float*)d_in[5];
    float* out = (float*)d_out;

    char* wsb = (char*)d_ws;
    unsigned short* M2Thi  = (unsigned short*)(wsb);              // 128 KB
    unsigned short* M2Tlo  = (unsigned short*)(wsb + 0x0020000);  // 128 KB
    float*          v      = (float*)(wsb + 0x0040000);           // 1 KB
    unsigned short* wbf    = (unsigned short*)(wsb + 0x0048000);  // 16 KB
    unsigned short* Awhi   = (unsigned short*)(wsb + 0x0100000);  // 4 MB
    unsigned short* Awlo   = (unsigned short*)(wsb + 0x0500000);  // 4 MB
    unsigned short* GT     = (unsigned short*)(wsb + 0x0900000);  // 4 MB
    float*          rspart = (float*)(wsb + 0x0D00000);           // 256 KB
    unsigned short* part   = (unsigned short*)(wsb + 0x1000000);  // 32 MB (NKB x 4 MB)

    k_M2v<<<255, 256, 0, stream>>>(Wg, Wa, aatt, M2Thi, M2Tlo, v);
    k_logw<<<N_ROWS / 8, 256, 0, stream>>>(x, v, wbf, Awhi, Awlo);
    k_hGT<<<N_ROWS / 64, 512, 0, stream>>>(M2Thi, M2Tlo, Awhi, Awlo, GT);
    k_attadj<<<32 * NKB, 512, 0, stream>>>(adj, GT, wbf, part, rspart);
    k_final3<<<N_ROWS, 256, 0, stream>>>(part, rspart, out);
}

// Round 19
// 155.305 us; speedup vs baseline: 1.4638x; 1.1038x over previous
//
#include <hip/hip_runtime.h>
#include <hip/hip_bf16.h>
#include <math.h>

typedef __attribute__((ext_vector_type(4))) float f32x4;
typedef __attribute__((ext_vector_type(8))) short bf16x8;

#define N_ROWS 8192
#define D 256
#define MSHIFT 16.0f
#define NKB 8
#define KRANGE (N_ROWS / NKB)     // 1024
#define NSTEP (KRANGE / 32)       // 32 (BK=32)

__device__ __forceinline__ unsigned short f2bf(float f) {
    unsigned int u = __float_as_uint(f);
    unsigned int r = u + 0x7FFFu + ((u >> 16) & 1u);
    return (unsigned short)(r >> 16);
}
__device__ __forceinline__ float bf2f(unsigned short h) {
    return __uint_as_float(((unsigned int)h) << 16);
}

__device__ __forceinline__ float breduce_sum256(float v, float* sb) {
#pragma unroll
    for (int off = 32; off; off >>= 1) v += __shfl_down(v, off);
    int wid = threadIdx.x >> 6;
    __syncthreads();
    if ((threadIdx.x & 63) == 0) sb[wid] = v;
    __syncthreads();
    return sb[0] + sb[1] + sb[2] + sb[3];
}

__device__ __forceinline__ void dma16(const void* g, void* l) {
    __builtin_amdgcn_global_load_lds(
        (const __attribute__((address_space(1))) unsigned int*)g,
        (__attribute__((address_space(3))) unsigned int*)l, 16, 0, 0);
}

__device__ __forceinline__ bf16x8 adj2bf(int4 a, int4 b) {
    bf16x8 r;
    r[0] = a.x ? (short)0x3F80 : (short)0;
    r[1] = a.y ? (short)0x3F80 : (short)0;
    r[2] = a.z ? (short)0x3F80 : (short)0;
    r[3] = a.w ? (short)0x3F80 : (short)0;
    r[4] = b.x ? (short)0x3F80 : (short)0;
    r[5] = b.y ? (short)0x3F80 : (short)0;
    r[6] = b.z ? (short)0x3F80 : (short)0;
    r[7] = b.w ? (short)0x3F80 : (short)0;
    return r;
}

// K1: M2 row k (f32) -> M2T hi/lo bf16 split [j][k]; v[k] = sum_j M2[k][j]*a2[j]
__global__ void k_M2v(const float* __restrict__ Wg, const float* __restrict__ Wa,
                      const float* __restrict__ aatt,
                      unsigned short* __restrict__ M2Thi, unsigned short* __restrict__ M2Tlo,
                      float* __restrict__ v) {
    __shared__ float sb[4];
    int k = blockIdx.x, t = threadIdx.x;
    float acc = 0.f;
#pragma unroll 8
    for (int m = 0; m < 255; ++m)
        acc += Wg[k * 255 + m] * Wa[(m + 1) * 256 + t];
    unsigned short hi = f2bf(acc);
    unsigned short lo = f2bf(acc - bf2f(hi));
    M2Thi[t * 256 + k] = hi;
    M2Tlo[t * 256 + k] = lo;
    if (k == 0) { M2Thi[t * 256 + 255] = 0; M2Tlo[t * 256 + 255] = 0; }
    float s = breduce_sum256(acc * aatt[256 + t], sb);
    if (t == 0) v[k] = s;
}

// K2: per-row logmap0 + c = logx.v + wexp; write wbf (bf16) and w-scaled logx hi/lo bf16
__global__ void k_logw(const float* __restrict__ x, const float* __restrict__ v,
                       unsigned short* __restrict__ wbf,
                       unsigned short* __restrict__ Awhi, unsigned short* __restrict__ Awlo) {
    __shared__ float sb[4];
    int i0 = blockIdx.x * 8, t = threadIdx.x;
    float vv = (t >= 1) ? v[t - 1] : 0.f;
#pragma unroll
    for (int r = 0; r < 8; ++r) {
        float xv = x[(size_t)(i0 + r) * D + t];
        float yv = (t >= 1) ? xv : 0.f;
        float ss = breduce_sum256(yv * yv, sb);
        float x0 = x[(size_t)(i0 + r) * D];
        float coef = acoshf(fmaxf(x0, 1.f + 1e-7f)) / fmaxf(sqrtf(ss), 1e-15f);
        float lg = coef * yv;                 // logx[i][t]
        float c = breduce_sum256(lg * vv, sb);
        float w = expf(c - MSHIFT);
        if (t == r) wbf[i0 + r] = f2bf(w);
        float aw = w * lg;
        unsigned short hi = f2bf(aw);
        unsigned short lo = f2bf(aw - bf2f(hi));
        int kd = (t == 0) ? 255 : (t - 1);    // Aw[i][k] = w*logx[i][k+1], pad k=255 -> 0
        Awhi[(size_t)(i0 + r) * 256 + kd] = hi;
        Awlo[(size_t)(i0 + r) * 256 + kd] = lo;
    }
}

// K3: GT[c][i] = sum_k M2T[c][k] * Aw[i][k]  (3-term hi/lo MFMA). 512 thr, 64 i-cols/block.
__global__ void __launch_bounds__(512)
k_hGT(const unsigned short* __restrict__ M2Thi, const unsigned short* __restrict__ M2Tlo,
      const unsigned short* __restrict__ Awhi, const unsigned short* __restrict__ Awlo,
      unsigned short* __restrict__ GT) {
    __shared__ __align__(16) char ahi[32768], alo[32768], bhi[8192], blo[8192];
    const int tid = threadIdx.x;
    const int w = tid >> 6, l = tid & 63;
    const int lr = l & 15, lq = l >> 4;
    const int i0 = blockIdx.x * 64;
    const int gs = (l & 7) ^ (l >> 3);

    const unsigned short* srcAhi[4];
    const unsigned short* srcAlo[4];
#pragma unroll
    for (int i = 0; i < 4; ++i) {
        int rowA = (w * 4 + i) * 8 + (l >> 3);
        srcAhi[i] = M2Thi + rowA * 256 + gs * 8;
        srcAlo[i] = M2Tlo + rowA * 256 + gs * 8;
    }
    int rowB = w * 8 + (l >> 3);
    const unsigned short* srcBhi = Awhi + (size_t)(i0 + rowB) * 256 + gs * 8;
    const unsigned short* srcBlo = Awlo + (size_t)(i0 + rowB) * 256 + gs * 8;

    f32x4 zero4 = {0.f, 0.f, 0.f, 0.f};
    f32x4 acc[2][4];
#pragma unroll
    for (int m = 0; m < 2; ++m)
#pragma unroll
        for (int n = 0; n < 4; ++n) acc[m][n] = zero4;

    for (int t = 0; t < 4; ++t) {
        if (t) __syncthreads();
#pragma unroll
        for (int i = 0; i < 4; ++i) {
            dma16(srcAhi[i] + t * 64, ahi + (w * 4 + i) * 1024);
            dma16(srcAlo[i] + t * 64, alo + (w * 4 + i) * 1024);
        }
        dma16(srcBhi + t * 64, bhi + w * 1024);
        dma16(srcBlo + t * 64, blo + w * 1024);
        asm volatile("s_waitcnt vmcnt(0)" ::: "memory");
        __syncthreads();
#pragma unroll
        for (int ks = 0; ks < 2; ++ks) {
            const int g = ((ks * 4 + lq) ^ (lr & 7)) * 16;
            bf16x8 afh[2], afl[2];
#pragma unroll
            for (int m = 0; m < 2; ++m) {
                int row = w * 32 + m * 16 + lr;
                afh[m] = *(const bf16x8*)(ahi + row * 128 + g);
                afl[m] = *(const bf16x8*)(alo + row * 128 + g);
            }
#pragma unroll
            for (int n = 0; n < 4; ++n) {
                int rb = n * 16 + lr;
                bf16x8 bfh = *(const bf16x8*)(bhi + rb * 128 + g);
                bf16x8 bfl = *(const bf16x8*)(blo + rb * 128 + g);
#pragma unroll
                for (int m = 0; m < 2; ++m) {
                    acc[m][n] = __builtin_amdgcn_mfma_f32_16x16x32_bf16(afh[m], bfh, acc[m][n], 0, 0, 0);
                    acc[m][n] = __builtin_amdgcn_mfma_f32_16x16x32_bf16(afh[m], bfl, acc[m][n], 0, 0, 0);
                    acc[m][n] = __builtin_amdgcn_mfma_f32_16x16x32_bf16(afl[m], bfh, acc[m][n], 0, 0, 0);
                }
            }
        }
    }
#pragma unroll
    for (int m = 0; m < 2; ++m)
#pragma unroll
        for (int n = 0; n < 4; ++n)
#pragma unroll
            for (int vv = 0; vv < 4; ++vv) {
                int c = w * 32 + m * 16 + lq * 4 + vv;
                GT[(size_t)c * N_ROWS + i0 + n * 16 + lr] = f2bf(acc[m][n][vv]);
            }
}

// K4: fused masked GEMM — EXACT R12 structure/schedule (best measured: 156.6 total),
// single change: part stored bf16. BM=256, BN=256, BK=32, NKB=8, 512 thr (4m x 2n).
// Triple-buffered; STAGE(t+1) issued BEFORE wait vmcnt(6); one s_barrier/step.
// kb=blockIdx&7 -> XCD-pinned 512 KB GT slice. Rowsum folded as wexp B-column.
__global__ void __launch_bounds__(512, 2)
k_attadj(const int* __restrict__ adj, const unsigned short* __restrict__ GT,
         const unsigned short* __restrict__ wbf, unsigned short* __restrict__ part,
         float* __restrict__ rspart) {
    __shared__ __align__(16) char bufA[3 * 32768];   // 256 rows x 32 ints (128 B rows)
    __shared__ __align__(16) char bufB[3 * 16384];   // 256 cols x 32 bf16 (64 B rows)
    __shared__ __align__(16) char wlds[2048];        // KRANGE bf16 weights
    const int tid = threadIdx.x;
    const int kb = blockIdx.x & 7;         // XCD-pinned GT k-slice
    const int rb = blockIdx.x >> 3;        // 0..31
    const int i0 = rb * 256;
    const int kbeg = kb * KRANGE;
    const int w = tid >> 6, l = tid & 63;
    const int lr = l & 15, lq = l >> 4;
    const int wm = w >> 1, wn = w & 1;     // 4 row-groups x 2 col-groups

    // A dma: 32 insts (4/wave): inst a covers rows a*8..+7; lane: row8=l>>3,
    // granule g=l&7 (16B=4 ints); LDS[row][g] = global[row][g ^ (row&7)]
    const int row8 = l >> 3, gA = (l & 7) ^ row8;
    const int* srcA[4];
#pragma unroll
    for (int i = 0; i < 4; ++i) {
        int a = w * 4 + i;
        srcA[i] = adj + (size_t)(i0 + a * 8 + row8) * N_ROWS + kbeg + gA * 4;
    }
    // B dma: 16 insts (2/wave): inst b covers cols b*16..+15; lane: col4=l>>2,
    // g2 (16B=8 bf16); LDS[col][g2] = global[col][g2 ^ (col&3)]
    const int col4 = l >> 2, gB = ((l & 3) ^ (col4 & 3)) * 8;
    const unsigned short* srcB[2];
#pragma unroll
    for (int i = 0; i < 2; ++i) {
        int b = w * 2 + i;
        srcB[i] = GT + (size_t)(b * 16 + col4) * N_ROWS + kbeg + gB;
    }

#define STAGE(T_, BI_) do {                                                \
        _Pragma("unroll")                                                  \
        for (int i_ = 0; i_ < 4; ++i_)                                     \
            dma16(srcA[i_] + (T_) * 32, bufA + (BI_) * 32768 + (w * 4 + i_) * 1024); \
        _Pragma("unroll")                                                  \
        for (int i_ = 0; i_ < 2; ++i_)                                     \
            dma16(srcB[i_] + (T_) * 32, bufB + (BI_) * 16384 + (w * 2 + i_) * 1024); \
    } while (0)

    f32x4 zero4 = {0.f, 0.f, 0.f, 0.f};
    f32x4 acc[4][8], acc_rs[4];
#pragma unroll
    for (int m = 0; m < 4; ++m) {
        acc_rs[m] = zero4;
#pragma unroll
        for (int n = 0; n < 8; ++n) acc[m][n] = zero4;
    }

    // prologue: stage step 0 + weight tile (6-7 dma outstanding per wave)
    STAGE(0, 0);
    if (w < 2) dma16(wbf + kbeg + w * 512 + l * 8, wlds + w * 1024);

    int cb = 0;
    for (int t = 0; t < NSTEP; ++t) {
        int nb = (cb == 2) ? 0 : cb + 1;
        if (t + 1 < NSTEP) {
            STAGE(t + 1, nb);
            asm volatile("s_waitcnt vmcnt(6)" ::: "memory");   // drains STAGE(t) (+wlds at t=0)
        } else {
            asm volatile("s_waitcnt vmcnt(0)" ::: "memory");
        }
        __builtin_amdgcn_sched_barrier(0);
        __builtin_amdgcn_s_barrier();
        __builtin_amdgcn_sched_barrier(0);

        const char* bA = bufA + cb * 32768;
        const char* bB = bufB + cb * 16384;

        bf16x8 wf = {0, 0, 0, 0, 0, 0, 0, 0};
        if (lr == 0) wf = *(const bf16x8*)(wlds + t * 64 + lq * 16);

        bf16x8 af[4];
#pragma unroll
        for (int m = 0; m < 4; ++m) {
            int row = wm * 64 + m * 16 + lr;
            int4 u  = *(const int4*)(bA + row * 128 + (((2 * lq) ^ (lr & 7)) << 4));
            int4 v2 = *(const int4*)(bA + row * 128 + (((2 * lq + 1) ^ (lr & 7)) << 4));
            af[m] = adj2bf(u, v2);
            acc_rs[m] = __builtin_amdgcn_mfma_f32_16x16x32_bf16(af[m], wf, acc_rs[m], 0, 0, 0);
        }
#pragma unroll
        for (int n = 0; n < 8; ++n) {
            int col = wn * 128 + n * 16 + lr;
            bf16x8 bf = *(const bf16x8*)(bB + col * 64 + ((lq ^ (lr & 3)) << 4));
#pragma unroll
            for (int m = 0; m < 4; ++m)
                acc[m][n] = __builtin_amdgcn_mfma_f32_16x16x32_bf16(af[m], bf, acc[m][n], 0, 0, 0);
        }
        cb = nb;
    }
#undef STAGE

    // rowsum (col 0 of acc_rs; wn duplicates -> wn==0 writes)
    if (wn == 0 && lr == 0) {
#pragma unroll
        for (int m = 0; m < 4; ++m)
#pragma unroll
            for (int vv = 0; vv < 4; ++vv)
                rspart[(size_t)kb * N_ROWS + i0 + wm * 64 + m * 16 + lq * 4 + vv] = acc_rs[m][vv];
    }

    // C write bf16 (layout: col=lane&15, row=(lane>>4)*4+reg); nontemporal
    unsigned short* pbase = part + (size_t)kb * N_ROWS * D;
#pragma unroll
    for (int m = 0; m < 4; ++m)
#pragma unroll
        for (int n = 0; n < 8; ++n) {
            int orow = i0 + wm * 64 + m * 16 + lq * 4;
            int ocol = wn * 128 + n * 16 + lr;
            unsigned short* op = pbase + (size_t)orow * D + ocol;
#pragma unroll
            for (int vv = 0; vv < 4; ++vv)
                __builtin_nontemporal_store(f2bf(acc[m][n][vv]), op + (size_t)vv * D);
        }
}

// K5: split-K reduce (bf16 part) + epilogue (divide, elu, proj, logmap0, sigmoid, expmap0)
__global__ void k_final3(const unsigned short* __restrict__ part, const float* __restrict__ rspart,
                         float* __restrict__ out) {
    __shared__ float sb[4];
    int row = blockIdx.x, t = threadIdx.x;
    float raw = 0.f, rs = 0.f;
#pragma unroll
    for (int kbi = 0; kbi < NKB; ++kbi) {
        raw += bf2f(__builtin_nontemporal_load(&part[((size_t)kbi * N_ROWS + row) * D + t]));
        rs += rspart[(size_t)kbi * N_ROWS + row];
    }
    float hp = raw / rs;
    float ey = 0.f;
    if (t >= 1) ey = (hp > 0.f) ? hp : expm1f(hp);
    float ss = breduce_sum256(ey * ey, sb);
    float x0 = sqrtf(1.f + ss);
    float th = fmaxf(x0, 1.f + 1e-7f);
    float al = acoshf(th);
    float yn = fmaxf(sqrtf(ss), 1e-15f);
    float u = (t >= 1) ? (al * ey / yn) : 0.f;
    float s = 1.f / (1.f + expf(-u));
    float s2 = (t >= 1) ? s * s : 0.f;
    float ssn = breduce_sum256(s2, sb);
    float xn = fmaxf(sqrtf(ssn), 1e-15f);
    float sh = sinhf(xn);
    float yf = (t >= 1) ? (sh * s / xn) : 0.f;
    float sy = breduce_sum256(yf * yf, sb);
    float res = (t == 0) ? sqrtf(1.f + sy) : yf;
    out[(size_t)row * D + t] = res;
}

extern "C" void kernel_launch(void* const* d_in, const int* in_sizes, int n_in,
                              void* d_out, int out_size, void* d_ws, size_t ws_size,
                              hipStream_t stream) {
    const float* x    = (const float*)d_in[0];
    const int*   adj  = (const int*)d_in[1];
    const float* Wg   = (const float*)d_in[3];
    const float* Wa   = (const float*)d_in[4];
    const float* aatt = (const float*)d_in[5];
    float* out = (float*)d_out;

    char* wsb = (char*)d_ws;
    unsigned short* M2Thi  = (unsigned short*)(wsb);              // 128 KB
    unsigned short* M2Tlo  = (unsigned short*)(wsb + 0x0020000);  // 128 KB
    float*          v      = (float*)(wsb + 0x0040000);           // 1 KB
    unsigned short* wbf    = (unsigned short*)(wsb + 0x0048000);  // 16 KB
    unsigned short* Awhi   = (unsigned short*)(wsb + 0x0100000);  // 4 MB
    unsigned short* Awlo   = (unsigned short*)(wsb + 0x0500000);  // 4 MB
    unsigned short* GT     = (unsigned short*)(wsb + 0x0900000);  // 4 MB
    float*          rspart = (float*)(wsb + 0x0D00000);           // 256 KB
    unsigned short* part   = (unsigned short*)(wsb + 0x1000000);  // 32 MB (NKB x 4 MB)

    k_M2v<<<255, 256, 0, stream>>>(Wg, Wa, aatt, M2Thi, M2Tlo, v);
    k_logw<<<N_ROWS / 8, 256, 0, stream>>>(x, v, wbf, Awhi, Awlo);
    k_hGT<<<N_ROWS / 64, 512, 0, stream>>>(M2Thi, M2Tlo, Awhi, Awlo, GT);
    k_attadj<<<32 * NKB, 512, 0, stream>>>(adj, GT, wbf, part, rspart);
    k_final3<<<N_ROWS, 256, 0, stream>>>(part, rspart, out);
}

// Round 20
// 147.330 us; speedup vs baseline: 1.5430x; 1.0541x over previous
//
#include <hip/hip_runtime.h>
#include <hip/hip_bf16.h>
#include <math.h>

typedef __attribute__((ext_vector_type(4))) float f32x4;
typedef __attribute__((ext_vector_type(8))) short bf16x8;
typedef __attribute__((ext_vector_type(4))) unsigned short u16x4;

#define N_ROWS 8192
#define D 256
#define MSHIFT 16.0f
#define NKB 8
#define KRANGE (N_ROWS / NKB)     // 1024
#define NSTEP (KRANGE / 32)       // 32 (BK=32)

__device__ __forceinline__ unsigned short f2bf(float f) {
    unsigned int u = __float_as_uint(f);
    unsigned int r = u + 0x7FFFu + ((u >> 16) & 1u);
    return (unsigned short)(r >> 16);
}
__device__ __forceinline__ float bf2f(unsigned short h) {
    return __uint_as_float(((unsigned int)h) << 16);
}

__device__ __forceinline__ float breduce_sum256(float v, float* sb) {
#pragma unroll
    for (int off = 32; off; off >>= 1) v += __shfl_down(v, off);
    int wid = threadIdx.x >> 6;
    __syncthreads();
    if ((threadIdx.x & 63) == 0) sb[wid] = v;
    __syncthreads();
    return sb[0] + sb[1] + sb[2] + sb[3];
}

__device__ __forceinline__ void dma16(const void* g, void* l) {
    __builtin_amdgcn_global_load_lds(
        (const __attribute__((address_space(1))) unsigned int*)g,
        (__attribute__((address_space(3))) unsigned int*)l, 16, 0, 0);
}

__device__ __forceinline__ bf16x8 adj2bf(int4 a, int4 b) {
    bf16x8 r;
    r[0] = a.x ? (short)0x3F80 : (short)0;
    r[1] = a.y ? (short)0x3F80 : (short)0;
    r[2] = a.z ? (short)0x3F80 : (short)0;
    r[3] = a.w ? (short)0x3F80 : (short)0;
    r[4] = b.x ? (short)0x3F80 : (short)0;
    r[5] = b.y ? (short)0x3F80 : (short)0;
    r[6] = b.z ? (short)0x3F80 : (short)0;
    r[7] = b.w ? (short)0x3F80 : (short)0;
    return r;
}

// K1: M2 row k (f32) -> M2T hi/lo bf16 split [j][k]; v[k] = sum_j M2[k][j]*a2[j]
__global__ void k_M2v(const float* __restrict__ Wg, const float* __restrict__ Wa,
                      const float* __restrict__ aatt,
                      unsigned short* __restrict__ M2Thi, unsigned short* __restrict__ M2Tlo,
                      float* __restrict__ v) {
    __shared__ float sb[4];
    int k = blockIdx.x, t = threadIdx.x;
    float acc = 0.f;
#pragma unroll 8
    for (int m = 0; m < 255; ++m)
        acc += Wg[k * 255 + m] * Wa[(m + 1) * 256 + t];
    unsigned short hi = f2bf(acc);
    unsigned short lo = f2bf(acc - bf2f(hi));
    M2Thi[t * 256 + k] = hi;
    M2Tlo[t * 256 + k] = lo;
    if (k == 0) { M2Thi[t * 256 + 255] = 0; M2Tlo[t * 256 + 255] = 0; }
    float s = breduce_sum256(acc * aatt[256 + t], sb);
    if (t == 0) { v[k] = s; if (k == 0) v[255] = 0.f; }
}

// K2: wave-per-row logw (barrier-free). Lane covers source cols l*4+1..l*4+4
// (shifted so Aw[row][k]=w*logx[row][k+1] stores land at k=l*4..+3, coalesced).
__global__ void __launch_bounds__(512)
k_logw(const float* __restrict__ x, const float* __restrict__ v,
       unsigned short* __restrict__ wbf,
       unsigned short* __restrict__ Awhi, unsigned short* __restrict__ Awlo) {
    const int tid = threadIdx.x;
    const int w = tid >> 6, l = tid & 63;
    const int row = blockIdx.x * 8 + w;
    const float* xr = x + (size_t)row * D;
    float xv[4];
#pragma unroll
    for (int j = 0; j < 4; ++j) {
        int c = l * 4 + 1 + j;
        xv[j] = (c < 256) ? xr[c] : 0.f;
    }
    float ss = xv[0] * xv[0] + xv[1] * xv[1] + xv[2] * xv[2] + xv[3] * xv[3];
#pragma unroll
    for (int off = 32; off; off >>= 1) ss += __shfl_xor(ss, off);
    float x0 = xr[0];
    float coef = acoshf(fmaxf(x0, 1.f + 1e-7f)) / fmaxf(sqrtf(ss), 1e-15f);
    float lg[4];
#pragma unroll
    for (int j = 0; j < 4; ++j) lg[j] = coef * xv[j];
    float4 vv = *(const float4*)(v + l * 4);
    float cdot = lg[0] * vv.x + lg[1] * vv.y + lg[2] * vv.z + lg[3] * vv.w;
#pragma unroll
    for (int off = 32; off; off >>= 1) cdot += __shfl_xor(cdot, off);
    float wv = expf(cdot - MSHIFT);
    if (l == 0) wbf[row] = f2bf(wv);
    u16x4 hi4, lo4;
#pragma unroll
    for (int j = 0; j < 4; ++j) {
        float aw = wv * lg[j];
        unsigned short hi = f2bf(aw);
        hi4[j] = hi;
        lo4[j] = f2bf(aw - bf2f(hi));
    }
    *(u16x4*)(Awhi + (size_t)row * 256 + l * 4) = hi4;
    *(u16x4*)(Awlo + (size_t)row * 256 + l * 4) = lo4;
}

// K3: GT[c][i] = sum_k M2T[c][k] * Aw[i][k]  (3-term hi/lo MFMA).
// 512 thr, 32 i-cols/block, grid 256 (full CU utilization).
__global__ void __launch_bounds__(512)
k_hGT(const unsigned short* __restrict__ M2Thi, const unsigned short* __restrict__ M2Tlo,
      const unsigned short* __restrict__ Awhi, const unsigned short* __restrict__ Awlo,
      unsigned short* __restrict__ GT) {
    __shared__ __align__(16) char ahi[32768], alo[32768], bhi[4096], blo[4096];
    const int tid = threadIdx.x;
    const int w = tid >> 6, l = tid & 63;
    const int lr = l & 15, lq = l >> 4;
    const int i0 = blockIdx.x * 32;
    const int gs = (l & 7) ^ (l >> 3);

    const unsigned short* srcAhi[4];
    const unsigned short* srcAlo[4];
#pragma unroll
    for (int i = 0; i < 4; ++i) {
        int rowA = (w * 4 + i) * 8 + (l >> 3);
        srcAhi[i] = M2Thi + rowA * 256 + gs * 8;
        srcAlo[i] = M2Tlo + rowA * 256 + gs * 8;
    }
    // B: 4 KB/buffer/step; insts j=0..3 (hi: waves 0-3, lo: waves 4-7), rows j*8..+7
    const int jb = w & 3;
    const int rowB = jb * 8 + (l >> 3);
    const unsigned short* srcB = ((w < 4) ? Awhi : Awlo) + (size_t)(i0 + rowB) * 256 + gs * 8;
    char* dstB = ((w < 4) ? bhi : blo) + jb * 1024;

    f32x4 zero4 = {0.f, 0.f, 0.f, 0.f};
    f32x4 acc[2][2];
#pragma unroll
    for (int m = 0; m < 2; ++m)
#pragma unroll
        for (int n = 0; n < 2; ++n) acc[m][n] = zero4;

    for (int t = 0; t < 4; ++t) {
        if (t) __syncthreads();
#pragma unroll
        for (int i = 0; i < 4; ++i) {
            dma16(srcAhi[i] + t * 64, ahi + (w * 4 + i) * 1024);
            dma16(srcAlo[i] + t * 64, alo + (w * 4 + i) * 1024);
        }
        dma16(srcB + t * 64, dstB);
        asm volatile("s_waitcnt vmcnt(0)" ::: "memory");
        __syncthreads();
#pragma unroll
        for (int ks = 0; ks < 2; ++ks) {
            const int g = ((ks * 4 + lq) ^ (lr & 7)) * 16;
            bf16x8 afh[2], afl[2];
#pragma unroll
            for (int m = 0; m < 2; ++m) {
                int row = w * 32 + m * 16 + lr;
                afh[m] = *(const bf16x8*)(ahi + row * 128 + g);
                afl[m] = *(const bf16x8*)(alo + row * 128 + g);
            }
#pragma unroll
            for (int n = 0; n < 2; ++n) {
                int rb = n * 16 + lr;
                bf16x8 bfh = *(const bf16x8*)(bhi + rb * 128 + g);
                bf16x8 bfl = *(const bf16x8*)(blo + rb * 128 + g);
#pragma unroll
                for (int m = 0; m < 2; ++m) {
                    acc[m][n] = __builtin_amdgcn_mfma_f32_16x16x32_bf16(afh[m], bfh, acc[m][n], 0, 0, 0);
                    acc[m][n] = __builtin_amdgcn_mfma_f32_16x16x32_bf16(afh[m], bfl, acc[m][n], 0, 0, 0);
                    acc[m][n] = __builtin_amdgcn_mfma_f32_16x16x32_bf16(afl[m], bfh, acc[m][n], 0, 0, 0);
                }
            }
        }
    }
#pragma unroll
    for (int m = 0; m < 2; ++m)
#pragma unroll
        for (int n = 0; n < 2; ++n)
#pragma unroll
            for (int vv = 0; vv < 4; ++vv) {
                int c = w * 32 + m * 16 + lq * 4 + vv;
                GT[(size_t)c * N_ROWS + i0 + n * 16 + lr] = f2bf(acc[m][n][vv]);
            }
}

// K4: fused masked GEMM — EXACT R19 (best measured). BM=256, BN=256, BK=32, NKB=8,
// 512 thr (4m x 2n). Triple-buffered; STAGE(t+1) BEFORE wait vmcnt(6); one
// s_barrier/step. kb=blockIdx&7 -> XCD-pinned GT slice. bf16 part.
__global__ void __launch_bounds__(512, 2)
k_attadj(const int* __restrict__ adj, const unsigned short* __restrict__ GT,
         const unsigned short* __restrict__ wbf, unsigned short* __restrict__ part,
         float* __restrict__ rspart) {
    __shared__ __align__(16) char bufA[3 * 32768];   // 256 rows x 32 ints (128 B rows)
    __shared__ __align__(16) char bufB[3 * 16384];   // 256 cols x 32 bf16 (64 B rows)
    __shared__ __align__(16) char wlds[2048];        // KRANGE bf16 weights
    const int tid = threadIdx.x;
    const int kb = blockIdx.x & 7;         // XCD-pinned GT k-slice
    const int rb = blockIdx.x >> 3;        // 0..31
    const int i0 = rb * 256;
    const int kbeg = kb * KRANGE;
    const int w = tid >> 6, l = tid & 63;
    const int lr = l & 15, lq = l >> 4;
    const int wm = w >> 1, wn = w & 1;     // 4 row-groups x 2 col-groups

    const int row8 = l >> 3, gA = (l & 7) ^ row8;
    const int* srcA[4];
#pragma unroll
    for (int i = 0; i < 4; ++i) {
        int a = w * 4 + i;
        srcA[i] = adj + (size_t)(i0 + a * 8 + row8) * N_ROWS + kbeg + gA * 4;
    }
    const int col4 = l >> 2, gB = ((l & 3) ^ (col4 & 3)) * 8;
    const unsigned short* srcB[2];
#pragma unroll
    for (int i = 0; i < 2; ++i) {
        int b = w * 2 + i;
        srcB[i] = GT + (size_t)(b * 16 + col4) * N_ROWS + kbeg + gB;
    }

#define STAGE(T_, BI_) do {                                                \
        _Pragma("unroll")                                                  \
        for (int i_ = 0; i_ < 4; ++i_)                                     \
            dma16(srcA[i_] + (T_) * 32, bufA + (BI_) * 32768 + (w * 4 + i_) * 1024); \
        _Pragma("unroll")                                                  \
        for (int i_ = 0; i_ < 2; ++i_)                                     \
            dma16(srcB[i_] + (T_) * 32, bufB + (BI_) * 16384 + (w * 2 + i_) * 1024); \
    } while (0)

    f32x4 zero4 = {0.f, 0.f, 0.f, 0.f};
    f32x4 acc[4][8], acc_rs[4];
#pragma unroll
    for (int m = 0; m < 4; ++m) {
        acc_rs[m] = zero4;
#pragma unroll
        for (int n = 0; n < 8; ++n) acc[m][n] = zero4;
    }

    STAGE(0, 0);
    if (w < 2) dma16(wbf + kbeg + w * 512 + l * 8, wlds + w * 1024);

    int cb = 0;
    for (int t = 0; t < NSTEP; ++t) {
        int nb = (cb == 2) ? 0 : cb + 1;
        if (t + 1 < NSTEP) {
            STAGE(t + 1, nb);
            asm volatile("s_waitcnt vmcnt(6)" ::: "memory");
        } else {
            asm volatile("s_waitcnt vmcnt(0)" ::: "memory");
        }
        __builtin_amdgcn_sched_barrier(0);
        __builtin_amdgcn_s_barrier();
        __builtin_amdgcn_sched_barrier(0);

        const char* bA = bufA + cb * 32768;
        const char* bB = bufB + cb * 16384;

        bf16x8 wf = {0, 0, 0, 0, 0, 0, 0, 0};
        if (lr == 0) wf = *(const bf16x8*)(wlds + t * 64 + lq * 16);

        bf16x8 af[4];
#pragma unroll
        for (int m = 0; m < 4; ++m) {
            int row = wm * 64 + m * 16 + lr;
            int4 u  = *(const int4*)(bA + row * 128 + (((2 * lq) ^ (lr & 7)) << 4));
            int4 v2 = *(const int4*)(bA + row * 128 + (((2 * lq + 1) ^ (lr & 7)) << 4));
            af[m] = adj2bf(u, v2);
            acc_rs[m] = __builtin_amdgcn_mfma_f32_16x16x32_bf16(af[m], wf, acc_rs[m], 0, 0, 0);
        }
#pragma unroll
        for (int n = 0; n < 8; ++n) {
            int col = wn * 128 + n * 16 + lr;
            bf16x8 bf = *(const bf16x8*)(bB + col * 64 + ((lq ^ (lr & 3)) << 4));
#pragma unroll
            for (int m = 0; m < 4; ++m)
                acc[m][n] = __builtin_amdgcn_mfma_f32_16x16x32_bf16(af[m], bf, acc[m][n], 0, 0, 0);
        }
        cb = nb;
    }
#undef STAGE

    if (wn == 0 && lr == 0) {
#pragma unroll
        for (int m = 0; m < 4; ++m)
#pragma unroll
            for (int vv = 0; vv < 4; ++vv)
                rspart[(size_t)kb * N_ROWS + i0 + wm * 64 + m * 16 + lq * 4 + vv] = acc_rs[m][vv];
    }

    unsigned short* pbase = part + (size_t)kb * N_ROWS * D;
#pragma unroll
    for (int m = 0; m < 4; ++m)
#pragma unroll
        for (int n = 0; n < 8; ++n) {
            int orow = i0 + wm * 64 + m * 16 + lq * 4;
            int ocol = wn * 128 + n * 16 + lr;
            unsigned short* op = pbase + (size_t)orow * D + ocol;
#pragma unroll
            for (int vv = 0; vv < 4; ++vv)
                __builtin_nontemporal_store(f2bf(acc[m][n][vv]), op + (size_t)vv * D);
        }
}

// K5: split-K reduce (bf16 part) + epilogue
__global__ void k_final3(const unsigned short* __restrict__ part, const float* __restrict__ rspart,
                         float* __restrict__ out) {
    __shared__ float sb[4];
    int row = blockIdx.x, t = threadIdx.x;
    float raw = 0.f, rs = 0.f;
#pragma unroll
    for (int kbi = 0; kbi < NKB; ++kbi) {
        raw += bf2f(__builtin_nontemporal_load(&part[((size_t)kbi * N_ROWS + row) * D + t]));
        rs += rspart[(size_t)kbi * N_ROWS + row];
    }
    float hp = raw / rs;
    float ey = 0.f;
    if (t >= 1) ey = (hp > 0.f) ? hp : expm1f(hp);
    float ss = breduce_sum256(ey * ey, sb);
    float x0 = sqrtf(1.f + ss);
    float th = fmaxf(x0, 1.f + 1e-7f);
    float al = acoshf(th);
    float yn = fmaxf(sqrtf(ss), 1e-15f);
    float u = (t >= 1) ? (al * ey / yn) : 0.f;
    float s = 1.f / (1.f + expf(-u));
    float s2 = (t >= 1) ? s * s : 0.f;
    float ssn = breduce_sum256(s2, sb);
    float xn = fmaxf(sqrtf(ssn), 1e-15f);
    float sh = sinhf(xn);
    float yf = (t >= 1) ? (sh * s / xn) : 0.f;
    float sy = breduce_sum256(yf * yf, sb);
    float res = (t == 0) ? sqrtf(1.f + sy) : yf;
    out[(size_t)row * D + t] = res;
}

extern "C" void kernel_launch(void* const* d_in, const int* in_sizes, int n_in,
                              void* d_out, int out_size, void* d_ws, size_t ws_size,
                              hipStream_t stream) {
    const float* x    = (const float*)d_in[0];
    const int*   adj  = (const int*)d_in[1];
    const float* Wg   = (const float*)d_in[3];
    const float* Wa   = (const float*)d_in[4];
    const float* aatt = (const float*)d_in[5];
    float* out = (float*)d_out;

    char* wsb = (char*)d_ws;
    unsigned short* M2Thi  = (unsigned short*)(wsb);              // 128 KB
    unsigned short* M2Tlo  = (unsigned short*)(wsb + 0x0020000);  // 128 KB
    float*          v      = (float*)(wsb + 0x0040000);           // 1 KB
    unsigned short* wbf    = (unsigned short*)(wsb + 0x0048000);  // 16 KB
    unsigned short* Awhi   = (unsigned short*)(wsb + 0x0100000);  // 4 MB
    unsigned short* Awlo   = (unsigned short*)(wsb + 0x0500000);  // 4 MB
    unsigned short* GT     = (unsigned short*)(wsb + 0x0900000);  // 4 MB
    float*          rspart = (float*)(wsb + 0x0D00000);           // 256 KB
    unsigned short* part   = (unsigned short*)(wsb + 0x1000000);  // 32 MB (NKB x 4 MB)

    k_M2v<<<255, 256, 0, stream>>>(Wg, Wa, aatt, M2Thi, M2Tlo, v);
    k_logw<<<N_ROWS / 8, 512, 0, stream>>>(x, v, wbf, Awhi, Awlo);
    k_hGT<<<N_ROWS / 32, 512, 0, stream>>>(M2Thi, M2Tlo, Awhi, Awlo, GT);
    k_attadj<<<32 * NKB, 512, 0, stream>>>(adj, GT, wbf, part, rspart);
    k_final3<<<N_ROWS, 256, 0, stream>>>(part, rspart, out);
}